// Round 5
// baseline (603.990 us; speedup 1.0000x reference)
//
#include <hip/hip_runtime.h>

// B=32, H=W=64, C=384, ws=8, heads=12, hd=32; windows=2048, N=64 tokens.
// Path 1 (needs ~102MB d_ws): prep -> qkv_attn (4 win/block, 16 waves, M48xN32 split)
//                                  -> proj_gemm (128x128 tiles, window_reverse epilogue)
// Path 2 (fallback, small ws):  prep -> win_attn_fused (round-2 kernel)

typedef __attribute__((ext_vector_type(8))) short bf16x8;   // 8 bf16 (4 VGPR) MFMA A/B frag
typedef __attribute__((ext_vector_type(4))) float f32x4;    // MFMA C/D frag
typedef __attribute__((ext_vector_type(4))) short short4_t;

__device__ __forceinline__ short f2bf(float f) {
    union { float f; unsigned u; } v; v.f = f;
    unsigned r = v.u + 0x7fffu + ((v.u >> 16) & 1u);   // RNE
    return (short)(r >> 16);
}

__device__ __forceinline__ unsigned pk2(float a, float b) {   // 2xbf16 dword (a=low)
    return ((unsigned)(unsigned short)f2bf(b) << 16) | (unsigned short)f2bf(a);
}

__device__ __forceinline__ f32x4 mfma16(bf16x8 a, bf16x8 b, f32x4 c) {
    return __builtin_amdgcn_mfma_f32_16x16x32_bf16(a, b, c, 0, 0, 0);
}

__device__ __forceinline__ short4_t pack4(f32x4 v) {
    short4_t s;
    s.x = f2bf(v[0]); s.y = f2bf(v[1]); s.z = f2bf(v[2]); s.w = f2bf(v[3]);
    return s;
}

__device__ __forceinline__ void gload_lds16(const void* g, void* l) {
    __builtin_amdgcn_global_load_lds(
        (const __attribute__((address_space(1))) unsigned int*)g,
        (__attribute__((address_space(3))) unsigned int*)l, 16, 0, 0);
}

// ---- prep: swizzled per-head QKV weights (Q rows pre-scaled) + transposed proj ----
// wq_sw[h][o]: byte L=2*o holds W_t[row][k], row=L/768, k=((L%768)^((row&7)<<4))/2.
// rows 0..31 = Q dims (x scale), 32..63 = K, 64..95 = V. W_t[row][k]=wqkv[k][col(row,h)].
__global__ void prep_weights(const float* __restrict__ wqkv, const float* __restrict__ wproj,
                             short* __restrict__ wq_sw, short* __restrict__ wp_t) {
    const int QKV_ELEMS = 12 * 96 * 384;
    int i = blockIdx.x * 256 + threadIdx.x;
    if (i < QKV_ELEMS) {
        int h = i / (96 * 384);
        int o = i % (96 * 384);
        int row = o / 384;
        int kb = ((o % 384) * 2) ^ ((row & 7) << 4);
        int k = kb >> 1;
        int col = (row >> 5) * 384 + h * 32 + (row & 31);
        float w = wqkv[k * 1152 + col];
        if (row < 32) w *= 0.17677669529663687f;   // 32^-0.5 folded into Q
        wq_sw[i] = f2bf(w);
    } else if (i < QKV_ELEMS + 384 * 384) {
        int j = i - QKV_ELEMS;
        int n = j / 384, k = j % 384;
        wp_t[j] = f2bf(wproj[k * 384 + n]);
    }
}

// ================= Path 1, kernel A: QKV + attention, y -> ws (swizzled) ==========
// Wave split: wid = m*8 + n; m = dim-half (rows m*48..m*48+47 of W), n = token-group
// (window n>>1, tokens (n&1)*32..+31). m=0 waves: Q(dims 0..31)+K(0..15), keep Q in
// regs, run scores+softmax. m=1 waves: K(16..31)+V(0..31), issue W prefetch DMA.
// PV phase: wave wid -> (window wid>>2, quad wid&3).
__global__ __launch_bounds__(1024)
void qkv_attn(const float* __restrict__ x, const short* __restrict__ wq_sw,
              short* __restrict__ y_sw) {
    __shared__ short Wl[96 * 384];       // 73,728 B per-head swizzled QKV weights
    __shared__ short k_s[4][64 * 40];    // K [tok][dim]                20,480 B
    __shared__ short v_t[4][32 * 72];    // V^T [dim][tok]              18,432 B
    __shared__ short ps[4][64 * 72];     // P [q][k]                    36,864 B
    // total 149,504 B -> 1 block/CU, 16 waves = 4/SIMD

    const int tid   = threadIdx.x;
    const int lane  = tid & 63;
    const int wid   = tid >> 6;      // 0..15
    const int col16 = lane & 15;
    const int kgrp  = lane >> 4;     // 0..3
    const int m     = wid >> 3;      // dim-half
    const int n     = wid & 7;       // token-group
    const int w     = n >> 1;        // QKV-role window 0..3
    const int th    = n & 1;         // token half within window

    const int w2    = wid >> 2;      // PV-role window
    const int quad  = wid & 3;       // PV-role quad

    // ---- issue DMA of head-0 weights (all waves) ----
    for (int i = wid; i < 72; i += 16)
        gload_lds16(wq_sw + i * 512 + lane * 8, &Wl[i * 512]);

    // ---- x: 2 token-tiles -> registers (96 VGPR) ----
    bf16x8 xf[2][12];
    {
        const int winA = blockIdx.x * 4 + w;
        const int bA = winA >> 6, wiA = winA & 63, whrA = wiA >> 3, wwcA = wiA & 7;
        const float* xbase = x + (((bA * 64) + whrA * 8) * 64 + wwcA * 8) * 384;
#pragma unroll
        for (int nt = 0; nt < 2; ++nt) {
            int t = th * 32 + nt * 16 + col16;
            const float* xr = xbase + ((t >> 3) * 64 + (t & 7)) * 384;
#pragma unroll
            for (int kk = 0; kk < 12; ++kk) {
                const float* p0 = xr + kk * 32 + kgrp * 8;
                float4 a = *reinterpret_cast<const float4*>(p0);
                float4 c = *reinterpret_cast<const float4*>(p0 + 4);
                bf16x8 f;
                f[0] = f2bf(a.x); f[1] = f2bf(a.y); f[2] = f2bf(a.z); f[3] = f2bf(a.w);
                f[4] = f2bf(c.x); f[5] = f2bf(c.y); f[6] = f2bf(c.z); f[7] = f2bf(c.w);
                xf[nt][kk] = f;
            }
        }
    }

    // y addressing (PV role): token gtok, its A-tile row/mtile (proj GEMM image)
    const int winB = blockIdx.x * 4 + w2;
    const int gtok = winB * 64 + quad * 16 + col16;
    const int mtile = gtok >> 7, yrow = gtok & 127;
    char* ybase = (char*)y_sw + (size_t)mtile * 98304 + (size_t)yrow * 128;

    const int tokbase = th * 32;     // QKV-role token offset within window

    for (int h = 0; h < 12; ++h) {
        __syncthreads();   // B0: W(h) landed; k_s/v_t free (prev head PV done)

        // ---- QKV GEMM: 3 dim-tiles x 2 tok-tiles, 36 W-reads, 72 MFMA ----
        f32x4 acc[3][2];
#pragma unroll
        for (int i = 0; i < 3; ++i)
#pragma unroll
            for (int j = 0; j < 2; ++j) acc[i][j] = (f32x4){0.f, 0.f, 0.f, 0.f};

        if (m == 0) {          // rows 0..47: Q dims 0..31 (mt 0,1), K dims 0..15 (mt 2)
#pragma unroll
            for (int kk = 0; kk < 12; ++kk) {
                const int kbyte = kk * 64 + kgrp * 16;
#pragma unroll
                for (int mt = 0; mt < 3; ++mt) {
                    const int row = mt * 16 + col16;
                    const bf16x8 wf = *reinterpret_cast<const bf16x8*>(
                        (const char*)Wl + row * 768 + (kbyte ^ ((row & 7) << 4)));
#pragma unroll
                    for (int nt = 0; nt < 2; ++nt)
                        acc[mt][nt] = mfma16(wf, xf[nt][kk], acc[mt][nt]);
                }
            }
        } else {               // rows 48..95: K dims 16..31 (mt 0), V dims 0..31 (mt 1,2)
#pragma unroll
            for (int kk = 0; kk < 12; ++kk) {
                const int kbyte = kk * 64 + kgrp * 16;
                {
                    const int row = 48 + col16;
                    const bf16x8 wf = *reinterpret_cast<const bf16x8*>(
                        (const char*)Wl + row * 768 + (kbyte ^ ((row & 7) << 4)));
#pragma unroll
                    for (int nt = 0; nt < 2; ++nt)
                        acc[0][nt] = mfma16(wf, xf[nt][kk], acc[0][nt]);
                }
#pragma unroll
                for (int vt = 0; vt < 2; ++vt) {
                    const int row = 64 + vt * 16 + col16;
                    const bf16x8 wf = *reinterpret_cast<const bf16x8*>(
                        (const char*)Wl + row * 768 + (kbyte ^ ((row & 7) << 4)));
#pragma unroll
                    for (int nt = 0; nt < 2; ++nt)   // V as B-operand -> D[tok][dim]
                        acc[1 + vt][nt] = mfma16(xf[nt][kk], wf, acc[1 + vt][nt]);
                }
            }
        }

        // ---- scatters + in-register Q relayout ----
        bf16x8 qa[2];
        if (m == 0) {
            // Q relayout per tok-tile: acc[0]=dims 0..15, acc[1]=dims 16..31 (verified r4)
#pragma unroll
            for (int nt = 0; nt < 2; ++nt) {
                unsigned A0 = pk2(acc[0][nt][0], acc[0][nt][1]);
                unsigned A1 = pk2(acc[0][nt][2], acc[0][nt][3]);
                unsigned B0 = pk2(acc[1][nt][0], acc[1][nt][1]);
                unsigned B1 = pk2(acc[1][nt][2], acc[1][nt][3]);
                int s0 = ((kgrp & 1) * 2) * 16 + col16;
                int a0 = __shfl((int)A0, s0, 64),      a1 = __shfl((int)A1, s0, 64);
                int a2 = __shfl((int)A0, s0 + 16, 64), a3 = __shfl((int)A1, s0 + 16, 64);
                int b0 = __shfl((int)B0, s0, 64),      b1 = __shfl((int)B1, s0, 64);
                int b2 = __shfl((int)B0, s0 + 16, 64), b3 = __shfl((int)B1, s0 + 16, 64);
                union { int i[4]; bf16x8 v; } qu;
                const bool loHalf = (kgrp < 2);
                qu.i[0] = loHalf ? a0 : b0;
                qu.i[1] = loHalf ? a1 : b1;
                qu.i[2] = loHalf ? a2 : b2;
                qu.i[3] = loHalf ? a3 : b3;
                qa[nt] = qu.v;
            }
            // K dims 0..15 scatter
#pragma unroll
            for (int nt = 0; nt < 2; ++nt)
                *reinterpret_cast<short4_t*>(
                    &k_s[w][(tokbase + nt * 16 + col16) * 40 + kgrp * 4]) = pack4(acc[2][nt]);
        } else {
            // K dims 16..31 scatter
#pragma unroll
            for (int nt = 0; nt < 2; ++nt)
                *reinterpret_cast<short4_t*>(
                    &k_s[w][(tokbase + nt * 16 + col16) * 40 + 16 + kgrp * 4]) = pack4(acc[0][nt]);
            // V scatter: D[tok][dim] -> v_t[dim][tok]
#pragma unroll
            for (int vt = 0; vt < 2; ++vt)
#pragma unroll
                for (int nt = 0; nt < 2; ++nt)
                    *reinterpret_cast<short4_t*>(
                        &v_t[w][(vt * 16 + col16) * 72 + tokbase + nt * 16 + kgrp * 4]) =
                        pack4(acc[1 + vt][nt]);
        }

        __syncthreads();   // B1: K/V visible; Wl fully read

        if (m == 1) {      // W(h+1) prefetch on the waves that idle during softmax
            if (h < 11) {
                const short* src = wq_sw + (h + 1) * (96 * 384);
                for (int i = n; i < 72; i += 8)
                    gload_lds16(src + i * 512 + lane * 8, &Wl[i * 512]);
            }
        } else {
            // ---- scores: 2 q-tiles x 4 k-tiles (kf shared across q-tiles) ----
            bf16x8 kf[4];
#pragma unroll
            for (int kt = 0; kt < 4; ++kt)
                kf[kt] = *reinterpret_cast<const bf16x8*>(
                    &k_s[w][(kt * 16 + col16) * 40 + kgrp * 8]);
            f32x4 sc[2][4];
#pragma unroll
            for (int nt = 0; nt < 2; ++nt)
#pragma unroll
                for (int kt = 0; kt < 4; ++kt) {
                    f32x4 z = (f32x4){0.f, 0.f, 0.f, 0.f};
                    sc[nt][kt] = mfma16(qa[nt], kf[kt], z);
                }
            // ---- softmax: 8 independent row-chains ----
            float mx[2][4], sm[2][4];
#pragma unroll
            for (int nt = 0; nt < 2; ++nt)
#pragma unroll
                for (int r = 0; r < 4; ++r)
                    mx[nt][r] = fmaxf(fmaxf(sc[nt][0][r], sc[nt][1][r]),
                                      fmaxf(sc[nt][2][r], sc[nt][3][r]));
#pragma unroll
            for (int d = 1; d < 16; d <<= 1)
#pragma unroll
                for (int nt = 0; nt < 2; ++nt)
#pragma unroll
                    for (int r = 0; r < 4; ++r)
                        mx[nt][r] = fmaxf(mx[nt][r], __shfl_xor(mx[nt][r], d, 16));
#pragma unroll
            for (int nt = 0; nt < 2; ++nt)
#pragma unroll
                for (int r = 0; r < 4; ++r) {
                    sm[nt][r] = 0.f;
#pragma unroll
                    for (int kt = 0; kt < 4; ++kt) {
                        sc[nt][kt][r] = __expf(sc[nt][kt][r] - mx[nt][r]);
                        sm[nt][r] += sc[nt][kt][r];
                    }
                }
#pragma unroll
            for (int d = 1; d < 16; d <<= 1)
#pragma unroll
                for (int nt = 0; nt < 2; ++nt)
#pragma unroll
                    for (int r = 0; r < 4; ++r)
                        sm[nt][r] += __shfl_xor(sm[nt][r], d, 16);
#pragma unroll
            for (int nt = 0; nt < 2; ++nt)
#pragma unroll
                for (int r = 0; r < 4; ++r) {
                    float inv = 1.0f / sm[nt][r];
                    int prow = tokbase + nt * 16 + kgrp * 4 + r;
#pragma unroll
                    for (int kt = 0; kt < 4; ++kt)
                        ps[w][prow * 72 + kt * 16 + col16] = f2bf(sc[nt][kt][r] * inv);
                }
        }

        __syncthreads();   // B2: P visible

        // ---- PV (all 16 waves): wave -> (w2, quad); mfma(V^T, P) -> D[dim][q] ----
        f32x4 o2[2];
        o2[0] = (f32x4){0.f, 0.f, 0.f, 0.f};
        o2[1] = (f32x4){0.f, 0.f, 0.f, 0.f};
#pragma unroll
        for (int kt = 0; kt < 2; ++kt) {
            bf16x8 pb = *reinterpret_cast<const bf16x8*>(
                &ps[w2][(quad * 16 + col16) * 72 + kt * 32 + kgrp * 8]);
#pragma unroll
            for (int d = 0; d < 2; ++d) {
                bf16x8 va = *reinterpret_cast<const bf16x8*>(
                    &v_t[w2][(d * 16 + col16) * 72 + kt * 32 + kgrp * 8]);
                o2[d] = mfma16(va, pb, o2[d]);
            }
        }
        // ---- y write (swizzled proj-A image): token=col16-row, dims kgrp*4..+3 ----
#pragma unroll
        for (int d = 0; d < 2; ++d) {
            int c0 = h * 32 + d * 16 + kgrp * 4;
            int kchunk = c0 >> 6;
            int koff = (2 * (c0 & 63)) ^ ((yrow & 7) << 4);
            *reinterpret_cast<short4_t*>(ybase + kchunk * 16384 + koff) = pack4(o2[d]);
        }
    }
}

// ================= Path 1, kernel B: out = y @ wp + bias, window_reverse ==========
__global__ __launch_bounds__(256)
void proj_gemm(const short* __restrict__ y_sw, const short* __restrict__ wp_t,
               const float* __restrict__ b_proj, float* __restrict__ out) {
    __shared__ short At[2][128 * 64];   // 2 x 16 KiB swizzled A tiles

    const int tid = threadIdx.x, lane = tid & 63, wv = tid >> 6;
    const int col16 = lane & 15, kgrp = lane >> 4;
    const int wm = wv >> 1, wn = wv & 1;
    const int mtile = blockIdx.x;       // 0..1023
    const int nblk  = blockIdx.y;       // 0..2

    const short* asrc = y_sw + (size_t)mtile * 6 * 128 * 64;

    // prologue: stage kchunk 0
    for (int i = wv; i < 16; i += 4)
        gload_lds16(asrc + i * 512 + lane * 8, &At[0][i * 512]);

    const short* bptr[4];
#pragma unroll
    for (int nt = 0; nt < 4; ++nt)
        bptr[nt] = wp_t + (size_t)(nblk * 128 + wn * 64 + nt * 16 + col16) * 384;

    f32x4 acc[4][4];
#pragma unroll
    for (int i = 0; i < 4; ++i)
#pragma unroll
        for (int j = 0; j < 4; ++j) acc[i][j] = (f32x4){0.f, 0.f, 0.f, 0.f};

    int cur = 0;
    for (int ks = 0; ks < 6; ++ks) {
        __syncthreads();               // buf[cur] ready (vmcnt drained by barrier)
        if (ks < 5) {
            const short* src = asrc + (ks + 1) * (128 * 64);
            for (int i = wv; i < 16; i += 4)
                gload_lds16(src + i * 512 + lane * 8, &At[cur ^ 1][i * 512]);
        }
#pragma unroll
        for (int kk = 0; kk < 2; ++kk) {
            const int kbyte = kk * 64 + kgrp * 16;
            bf16x8 af[4];
#pragma unroll
            for (int mt = 0; mt < 4; ++mt) {
                const int r = wm * 64 + mt * 16 + col16;
                af[mt] = *reinterpret_cast<const bf16x8*>(
                    (const char*)At[cur] + r * 128 + (kbyte ^ ((r & 7) << 4)));
            }
#pragma unroll
            for (int nt = 0; nt < 4; ++nt) {
                bf16x8 bf = *reinterpret_cast<const bf16x8*>(bptr[nt] + ks * 64 + kk * 32 + kgrp * 8);
#pragma unroll
                for (int mt = 0; mt < 4; ++mt)
                    acc[mt][nt] = mfma16(af[mt], bf, acc[mt][nt]);
            }
        }
        cur ^= 1;
    }

    // epilogue: bias + window_reverse scatter
#pragma unroll
    for (int nt = 0; nt < 4; ++nt) {
        int c = nblk * 128 + wn * 64 + nt * 16 + col16;
        float bias = b_proj[c];
#pragma unroll
        for (int mt = 0; mt < 4; ++mt) {
#pragma unroll
            for (int r = 0; r < 4; ++r) {
                int gg = mtile * 128 + wm * 64 + mt * 16 + kgrp * 4 + r;
                int win = gg >> 6, t = gg & 63;
                int b = win >> 6, whr = (win >> 3) & 7, wwc = win & 7;
                int orow = (b * 64 + whr * 8 + (t >> 3)) * 64 + wwc * 8 + (t & 7);
                out[(size_t)orow * 384 + c] = acc[mt][nt][r] + bias;
            }
        }
    }
}

// ================= Path 2 fallback: round-2 fused kernel (scale in prep) ==========
__global__ __launch_bounds__(512, 2)
void win_attn_fused(const float* __restrict__ x, const short* __restrict__ wq_sw,
                    const short* __restrict__ wp_t, const float* __restrict__ b_proj,
                    float* __restrict__ out) {
    __shared__ short Wl[96 * 384];
    __shared__ short q_s[2][64 * 40];
    __shared__ short k_s[2][64 * 40];
    __shared__ short v_t[2][32 * 72];
    __shared__ short ps[2][64 * 72];

    const int tid   = threadIdx.x;
    const int lane  = tid & 63;
    const int wv    = tid >> 6;
    const int col16 = lane & 15;
    const int kgrp  = lane >> 4;
    const int wwin  = wv >> 2;
    const int q4    = wv & 3;
    const int wm    = q4 >> 1, wn = q4 & 1;

    const int win = blockIdx.x * 2 + wwin;
    const int b = win >> 6, wi = win & 63, whr = wi >> 3, wwc = wi & 7;
    const float* xbase = x + (((b * 64) + whr * 8) * 64 + wwc * 8) * 384;

    for (int i = 0; i < 9; ++i) {
        int chunk = wv * 9 + i;
        gload_lds16(wq_sw + chunk * 512 + lane * 8, &Wl[chunk * 512]);
    }
    bf16x8 xf[12];
    {
        int t = q4 * 16 + col16;
        const float* xr = xbase + ((t >> 3) * 64 + (t & 7)) * 384;
#pragma unroll
        for (int kk = 0; kk < 12; ++kk) {
            const float* p0 = xr + kk * 32 + kgrp * 8;
            float4 a = *reinterpret_cast<const float4*>(p0);
            float4 c = *reinterpret_cast<const float4*>(p0 + 4);
            bf16x8 f;
            f[0] = f2bf(a.x); f[1] = f2bf(a.y); f[2] = f2bf(a.z); f[3] = f2bf(a.w);
            f[4] = f2bf(c.x); f[5] = f2bf(c.y); f[6] = f2bf(c.z); f[7] = f2bf(c.w);
            xf[kk] = f;
        }
    }
    f32x4 pacc[2][12];
#pragma unroll
    for (int i = 0; i < 2; ++i)
#pragma unroll
        for (int j = 0; j < 12; ++j) pacc[i][j] = (f32x4){0.f, 0.f, 0.f, 0.f};

    for (int h = 0; h < 12; ++h) {
        __syncthreads();
        f32x4 acc[6];
#pragma unroll
        for (int i = 0; i < 6; ++i) acc[i] = (f32x4){0.f, 0.f, 0.f, 0.f};
#pragma unroll
        for (int kk = 0; kk < 12; ++kk) {
            const int kbyte = (kk * 32 + kgrp * 8) * 2;
#pragma unroll
            for (int rd = 0; rd < 6; ++rd) {
                const int row = (rd >> 1) * 32 + (rd & 1) * 16 + col16;
                const bf16x8 wf = *reinterpret_cast<const bf16x8*>(
                    (const char*)Wl + row * 768 + (kbyte ^ ((row & 7) << 4)));
                if (rd < 4) acc[rd] = mfma16(wf, xf[kk], acc[rd]);
                else        acc[rd] = mfma16(xf[kk], wf, acc[rd]);
            }
        }
#pragma unroll
        for (int rd = 0; rd < 4; ++rd) {
            short* dst = (rd < 2) ? q_s[wwin] : k_s[wwin];
            *reinterpret_cast<short4_t*>(
                &dst[(q4 * 16 + col16) * 40 + (rd & 1) * 16 + kgrp * 4]) = pack4(acc[rd]);
        }
#pragma unroll
        for (int d = 0; d < 2; ++d)
            *reinterpret_cast<short4_t*>(
                &v_t[wwin][(d * 16 + col16) * 72 + q4 * 16 + kgrp * 4]) = pack4(acc[4 + d]);

        __syncthreads();
        if (h < 11) {
            const short* src = wq_sw + (h + 1) * (96 * 384);
            for (int i = 0; i < 9; ++i) {
                int chunk = wv * 9 + i;
                gload_lds16(src + chunk * 512 + lane * 8, &Wl[chunk * 512]);
            }
        }
        bf16x8 qa = *reinterpret_cast<const bf16x8*>(
            &q_s[wwin][(q4 * 16 + col16) * 40 + kgrp * 8]);
        f32x4 sc[4];
#pragma unroll
        for (int nt = 0; nt < 4; ++nt) {
            bf16x8 kf = *reinterpret_cast<const bf16x8*>(
                &k_s[wwin][(nt * 16 + col16) * 40 + kgrp * 8]);
            f32x4 z = (f32x4){0.f, 0.f, 0.f, 0.f};
            sc[nt] = mfma16(qa, kf, z);
        }
        float mx[4], sm[4], p[4][4];
#pragma unroll
        for (int r = 0; r < 4; ++r)
            mx[r] = fmaxf(fmaxf(sc[0][r], sc[1][r]), fmaxf(sc[2][r], sc[3][r]));
#pragma unroll
        for (int d = 1; d < 16; d <<= 1)
#pragma unroll
            for (int r = 0; r < 4; ++r) mx[r] = fmaxf(mx[r], __shfl_xor(mx[r], d, 16));
#pragma unroll
        for (int r = 0; r < 4; ++r) {
            sm[r] = 0.f;
#pragma unroll
            for (int nt = 0; nt < 4; ++nt) { p[nt][r] = __expf(sc[nt][r] - mx[r]); sm[r] += p[nt][r]; }
        }
#pragma unroll
        for (int d = 1; d < 16; d <<= 1)
#pragma unroll
            for (int r = 0; r < 4; ++r) sm[r] += __shfl_xor(sm[r], d, 16);
#pragma unroll
        for (int r = 0; r < 4; ++r) {
            float inv = 1.0f / sm[r];
            int prow = q4 * 16 + kgrp * 4 + r;
#pragma unroll
            for (int nt = 0; nt < 4; ++nt)
                ps[wwin][prow * 72 + nt * 16 + col16] = f2bf(p[nt][r] * inv);
        }
        f32x4 o2[2];
        o2[0] = (f32x4){0.f, 0.f, 0.f, 0.f};
        o2[1] = (f32x4){0.f, 0.f, 0.f, 0.f};
#pragma unroll
        for (int kt = 0; kt < 2; ++kt) {
            bf16x8 pb = *reinterpret_cast<const bf16x8*>(
                &ps[wwin][(q4 * 16 + col16) * 72 + kt * 32 + kgrp * 8]);
#pragma unroll
            for (int d = 0; d < 2; ++d) {
                bf16x8 va = *reinterpret_cast<const bf16x8*>(
                    &v_t[wwin][(d * 16 + col16) * 72 + kt * 32 + kgrp * 8]);
                o2[d] = mfma16(va, pb, o2[d]);
            }
        }
#pragma unroll
        for (int d = 0; d < 2; ++d)
            *reinterpret_cast<short4_t*>(
                &ps[wwin][(q4 * 16 + col16) * 72 + d * 16 + kgrp * 4]) = pack4(o2[d]);
        __syncthreads();
#pragma unroll
        for (int mt = 0; mt < 2; ++mt) {
            bf16x8 ya = *reinterpret_cast<const bf16x8*>(
                &ps[wwin][(wm * 32 + mt * 16 + col16) * 72 + kgrp * 8]);
#pragma unroll
            for (int nt = 0; nt < 12; ++nt) {
                bf16x8 wb = *reinterpret_cast<const bf16x8*>(
                    &wp_t[(wn * 192 + nt * 16 + col16) * 384 + h * 32 + kgrp * 8]);
                pacc[mt][nt] = mfma16(ya, wb, pacc[mt][nt]);
            }
        }
    }
#pragma unroll
    for (int nt = 0; nt < 12; ++nt) {
        int c = wn * 192 + nt * 16 + col16;
        float bias = b_proj[c];
#pragma unroll
        for (int mt = 0; mt < 2; ++mt) {
#pragma unroll
            for (int r = 0; r < 4; ++r) {
                int token = wm * 32 + mt * 16 + kgrp * 4 + r;
                int hh = whr * 8 + (token >> 3);
                int ww2 = wwc * 8 + (token & 7);
                out[(((b * 64) + hh) * 64 + ww2) * 384 + c] = pacc[mt][nt][r] + bias;
            }
        }
    }
}

extern "C" void kernel_launch(void* const* d_in, const int* in_sizes, int n_in,
                              void* d_out, int out_size, void* d_ws, size_t ws_size,
                              hipStream_t stream) {
    const float* x     = (const float*)d_in[0];
    const float* wqkv  = (const float*)d_in[1];
    const float* wproj = (const float*)d_in[2];
    const float* bproj = (const float*)d_in[3];

    short* wq_sw = (short*)d_ws;                  // 884,736 B
    short* wp_t  = wq_sw + 12 * 96 * 384;         // 294,912 B
    short* y_sw  = wp_t + 384 * 384;              // 100,663,296 B (path 1 only)
    const size_t need = (size_t)(12 * 96 * 384 + 384 * 384) * 2 + (size_t)1024 * 6 * 128 * 128;

    prep_weights<<<2304, 256, 0, stream>>>(wqkv, wproj, wq_sw, wp_t);
    if (ws_size >= need) {
        qkv_attn<<<512, 1024, 0, stream>>>(x, wq_sw, y_sw);
        proj_gemm<<<dim3(1024, 3), 256, 0, stream>>>(y_sw, wp_t, bproj, (float*)d_out);
    } else {
        win_attn_fused<<<1024, 512, 0, stream>>>(x, wq_sw, wp_t, bproj, (float*)d_out);
    }
}

// Round 6
// 391.154 us; speedup vs baseline: 1.5441x; 1.5441x over previous
//
#include <hip/hip_runtime.h>

// B=32, H=W=64, C=384, ws=8, heads=12, hd=32; windows=2048, N=64 tokens.
// Path 1 (needs ~102MB d_ws): prep -> qkv_attn (4 win/block, 16 waves, r4 structure,
//   launch_bounds(1024,4) for 128 VGPR, conflict-free LDS strides)
//                                  -> proj_gemm (128x128 tiles, window_reverse epilogue)
// Path 2 (fallback, small ws):  prep -> win_attn_fused (round-2 kernel)

typedef __attribute__((ext_vector_type(8))) short bf16x8;   // 8 bf16 (4 VGPR) MFMA A/B frag
typedef __attribute__((ext_vector_type(4))) float f32x4;    // MFMA C/D frag
typedef __attribute__((ext_vector_type(4))) short short4_t;

__device__ __forceinline__ short f2bf(float f) {
    union { float f; unsigned u; } v; v.f = f;
    unsigned r = v.u + 0x7fffu + ((v.u >> 16) & 1u);   // RNE
    return (short)(r >> 16);
}

__device__ __forceinline__ unsigned pk2(float a, float b) {   // 2xbf16 dword (a=low)
    return ((unsigned)(unsigned short)f2bf(b) << 16) | (unsigned short)f2bf(a);
}

__device__ __forceinline__ f32x4 mfma16(bf16x8 a, bf16x8 b, f32x4 c) {
    return __builtin_amdgcn_mfma_f32_16x16x32_bf16(a, b, c, 0, 0, 0);
}

__device__ __forceinline__ short4_t pack4(f32x4 v) {
    short4_t s;
    s.x = f2bf(v[0]); s.y = f2bf(v[1]); s.z = f2bf(v[2]); s.w = f2bf(v[3]);
    return s;
}

__device__ __forceinline__ void gload_lds16(const void* g, void* l) {
    __builtin_amdgcn_global_load_lds(
        (const __attribute__((address_space(1))) unsigned int*)g,
        (__attribute__((address_space(3))) unsigned int*)l, 16, 0, 0);
}

// ---- prep: swizzled per-head QKV weights (Q rows pre-scaled) + transposed proj ----
// wq_sw[h][o]: byte L=2*o holds W_t[row][k], row=L/768, k=((L%768)^((row&7)<<4))/2.
// rows 0..31 = Q dims (x scale), 32..63 = K, 64..95 = V. W_t[row][k]=wqkv[k][col(row,h)].
__global__ void prep_weights(const float* __restrict__ wqkv, const float* __restrict__ wproj,
                             short* __restrict__ wq_sw, short* __restrict__ wp_t) {
    const int QKV_ELEMS = 12 * 96 * 384;
    int i = blockIdx.x * 256 + threadIdx.x;
    if (i < QKV_ELEMS) {
        int h = i / (96 * 384);
        int o = i % (96 * 384);
        int row = o / 384;
        int kb = ((o % 384) * 2) ^ ((row & 7) << 4);
        int k = kb >> 1;
        int col = (row >> 5) * 384 + h * 32 + (row & 31);
        float w = wqkv[k * 1152 + col];
        if (row < 32) w *= 0.17677669529663687f;   // 32^-0.5 folded into Q
        wq_sw[i] = f2bf(w);
    } else if (i < QKV_ELEMS + 384 * 384) {
        int j = i - QKV_ELEMS;
        int n = j / 384, k = j % 384;
        wp_t[j] = f2bf(wproj[k * 384 + n]);
    }
}

// ================= Path 1, kernel A: QKV + attention, y -> ws (swizzled) ==========
// Round-4 wave decomposition: wave wid -> (window wid>>2, quad wid&3); each wave owns
// 16 tokens and computes Q(regs)/K/V for them, then scores+softmax+PV+y-write.
// NEW vs r4: launch_bounds(1024,4) -> 128 VGPR (kills scratch spills);
//            k_s stride 44, v_t/ps stride 76 (16-bank-distinct row walks).
__global__ __launch_bounds__(1024, 4)
void qkv_attn(const float* __restrict__ x, const short* __restrict__ wq_sw,
              short* __restrict__ y_sw) {
    __shared__ short Wl[96 * 384];       // 73,728 B per-head swizzled QKV weights
    __shared__ short k_s[4][64 * 44];    // K [tok][dim]                22,528 B
    __shared__ short v_t[4][32 * 76];    // V^T [dim][tok]              19,456 B
    __shared__ short ps[4][64 * 76];     // P [q][k]                    38,912 B
    // total 154,624 B -> 1 block/CU, 16 waves = 4/SIMD

    const int tid   = threadIdx.x;
    const int lane  = tid & 63;
    const int wid   = tid >> 6;      // 0..15
    const int col16 = lane & 15;
    const int kgrp  = lane >> 4;     // 0..3
    const int w     = wid >> 2;      // window within block 0..3
    const int quad  = wid & 3;       // quad in window (owns token-tile quad)

    const int win = blockIdx.x * 4 + w;
    const int b = win >> 6, wi = win & 63, whr = wi >> 3, wwc = wi & 7;
    const float* xbase = x + (((b * 64) + whr * 8) * 64 + wwc * 8) * 384;

    // ---- issue DMA of head-0 weights ----
    for (int i = wid; i < 72; i += 16)
        gload_lds16(wq_sw + i * 512 + lane * 8, &Wl[i * 512]);

    // ---- x token-tile -> registers (48 VGPR) ----
    bf16x8 xf[12];
    {
        int t = quad * 16 + col16;
        const float* xr = xbase + ((t >> 3) * 64 + (t & 7)) * 384;
#pragma unroll
        for (int kk = 0; kk < 12; ++kk) {
            const float* p0 = xr + kk * 32 + kgrp * 8;
            float4 a = *reinterpret_cast<const float4*>(p0);
            float4 c = *reinterpret_cast<const float4*>(p0 + 4);
            bf16x8 f;
            f[0] = f2bf(a.x); f[1] = f2bf(a.y); f[2] = f2bf(a.z); f[3] = f2bf(a.w);
            f[4] = f2bf(c.x); f[5] = f2bf(c.y); f[6] = f2bf(c.z); f[7] = f2bf(c.w);
            xf[kk] = f;
        }
    }

    // y addressing: token g, its A-tile row/mtile (proj GEMM image)
    const int g = win * 64 + quad * 16 + col16;
    const int mtile = g >> 7, yrow = g & 127;
    char* ybase = (char*)y_sw + (size_t)mtile * 98304 + (size_t)yrow * 128;

    for (int h = 0; h < 12; ++h) {
        __syncthreads();   // B0: W(h) DMA drained; k_s/v_t free (prev head reads done)

        // ---- QKV: Q/K via mfma(W,x) -> D[dim][tok]; V via mfma(x,W) -> D[tok][dim] ----
        f32x4 acc[6];
#pragma unroll
        for (int i = 0; i < 6; ++i) acc[i] = (f32x4){0.f, 0.f, 0.f, 0.f};
#pragma unroll
        for (int kk = 0; kk < 12; ++kk) {
            const int kbyte = (kk * 32 + kgrp * 8) * 2;
#pragma unroll
            for (int rd = 0; rd < 6; ++rd) {    // 0,1=Q d0,d1; 2,3=K; 4,5=V
                const int row = (rd >> 1) * 32 + (rd & 1) * 16 + col16;
                const bf16x8 wf = *reinterpret_cast<const bf16x8*>(
                    (const char*)Wl + row * 768 + (kbyte ^ ((row & 7) << 4)));
                if (rd < 4) acc[rd] = mfma16(wf, xf[kk], acc[rd]);
                else        acc[rd] = mfma16(xf[kk], wf, acc[rd]);
            }
        }
        // ---- Q relayout D[dim][tok] -> A-frag[tok][dim], in-register (verified r4) ----
        bf16x8 qa;
        {
            unsigned A0 = pk2(acc[0][0], acc[0][1]);
            unsigned A1 = pk2(acc[0][2], acc[0][3]);
            unsigned B0 = pk2(acc[1][0], acc[1][1]);
            unsigned B1 = pk2(acc[1][2], acc[1][3]);
            int s0 = ((kgrp & 1) * 2) * 16 + col16;
            int a0 = __shfl((int)A0, s0, 64),      a1 = __shfl((int)A1, s0, 64);
            int a2 = __shfl((int)A0, s0 + 16, 64), a3 = __shfl((int)A1, s0 + 16, 64);
            int b0 = __shfl((int)B0, s0, 64),      b1 = __shfl((int)B1, s0, 64);
            int b2 = __shfl((int)B0, s0 + 16, 64), b3 = __shfl((int)B1, s0 + 16, 64);
            union { int i[4]; bf16x8 v; } qu;
            const bool loHalf = (kgrp < 2);
            qu.i[0] = loHalf ? a0 : b0;
            qu.i[1] = loHalf ? a1 : b1;
            qu.i[2] = loHalf ? a2 : b2;
            qu.i[3] = loHalf ? a3 : b3;
            qa = qu.v;
        }
        // ---- K scatter (b64): k_s[tok][dim], stride 44 ----
#pragma unroll
        for (int rd = 2; rd < 4; ++rd)
            *reinterpret_cast<short4_t*>(
                &k_s[w][(quad * 16 + col16) * 44 + (rd & 1) * 16 + kgrp * 4]) = pack4(acc[rd]);
        // ---- V scatter (b64): v_t[dim][tok], stride 76 ----
#pragma unroll
        for (int d = 0; d < 2; ++d)
            *reinterpret_cast<short4_t*>(
                &v_t[w][(d * 16 + col16) * 76 + quad * 16 + kgrp * 4]) = pack4(acc[4 + d]);

        __syncthreads();   // B1: K/V visible; Wl fully read -> safe to DMA next head

        if (h < 11) {
            const short* src = wq_sw + (h + 1) * (96 * 384);
            for (int i = wid; i < 72; i += 16)
                gload_lds16(src + i * 512 + lane * 8, &Wl[i * 512]);
        }

        // ---- scores: wave owns q-rows quad*16..+15 ----
        f32x4 sc[4];
#pragma unroll
        for (int nt = 0; nt < 4; ++nt) {
            bf16x8 kf = *reinterpret_cast<const bf16x8*>(
                &k_s[w][(nt * 16 + col16) * 44 + kgrp * 8]);
            f32x4 z = (f32x4){0.f, 0.f, 0.f, 0.f};
            sc[nt] = mfma16(qa, kf, z);
        }
        // ---- softmax (4 independent row-chains) ----
        float mx[4], sm[4];
#pragma unroll
        for (int r = 0; r < 4; ++r)
            mx[r] = fmaxf(fmaxf(sc[0][r], sc[1][r]), fmaxf(sc[2][r], sc[3][r]));
#pragma unroll
        for (int d = 1; d < 16; d <<= 1)
#pragma unroll
            for (int r = 0; r < 4; ++r) mx[r] = fmaxf(mx[r], __shfl_xor(mx[r], d, 16));
#pragma unroll
        for (int r = 0; r < 4; ++r) {
            sm[r] = 0.f;
#pragma unroll
            for (int nt = 0; nt < 4; ++nt) {
                sc[nt][r] = __expf(sc[nt][r] - mx[r]); sm[r] += sc[nt][r];
            }
        }
#pragma unroll
        for (int d = 1; d < 16; d <<= 1)
#pragma unroll
            for (int r = 0; r < 4; ++r) sm[r] += __shfl_xor(sm[r], d, 16);
#pragma unroll
        for (int r = 0; r < 4; ++r) {
            float inv = 1.0f / sm[r];
            int prow = quad * 16 + kgrp * 4 + r;
#pragma unroll
            for (int nt = 0; nt < 4; ++nt)
                ps[w][prow * 76 + nt * 16 + col16] = f2bf(sc[nt][r] * inv);
        }
        // ---- PV via mfma(V^T, P) -> D[dim][q]; wave-local ps rows, no barrier ----
        f32x4 o2[2];
        o2[0] = (f32x4){0.f, 0.f, 0.f, 0.f};
        o2[1] = (f32x4){0.f, 0.f, 0.f, 0.f};
#pragma unroll
        for (int kt = 0; kt < 2; ++kt) {
            bf16x8 pb = *reinterpret_cast<const bf16x8*>(
                &ps[w][(quad * 16 + col16) * 76 + kt * 32 + kgrp * 8]);
#pragma unroll
            for (int d = 0; d < 2; ++d) {
                bf16x8 va = *reinterpret_cast<const bf16x8*>(
                    &v_t[w][(d * 16 + col16) * 76 + kt * 32 + kgrp * 8]);
                o2[d] = mfma16(va, pb, o2[d]);
            }
        }
        // ---- y write (swizzled proj-A image): token=col16-row, dims kgrp*4..+3 ----
#pragma unroll
        for (int d = 0; d < 2; ++d) {
            int c0 = h * 32 + d * 16 + kgrp * 4;
            int kchunk = c0 >> 6;
            int koff = (2 * (c0 & 63)) ^ ((yrow & 7) << 4);
            *reinterpret_cast<short4_t*>(ybase + kchunk * 16384 + koff) = pack4(o2[d]);
        }
    }
}

// ================= Path 1, kernel B: out = y @ wp + bias, window_reverse ==========
__global__ __launch_bounds__(256)
void proj_gemm(const short* __restrict__ y_sw, const short* __restrict__ wp_t,
               const float* __restrict__ b_proj, float* __restrict__ out) {
    __shared__ short At[2][128 * 64];   // 2 x 16 KiB swizzled A tiles

    const int tid = threadIdx.x, lane = tid & 63, wv = tid >> 6;
    const int col16 = lane & 15, kgrp = lane >> 4;
    const int wm = wv >> 1, wn = wv & 1;
    const int mtile = blockIdx.x;       // 0..1023
    const int nblk  = blockIdx.y;       // 0..2

    const short* asrc = y_sw + (size_t)mtile * 6 * 128 * 64;

    // prologue: stage kchunk 0
    for (int i = wv; i < 16; i += 4)
        gload_lds16(asrc + i * 512 + lane * 8, &At[0][i * 512]);

    const short* bptr[4];
#pragma unroll
    for (int nt = 0; nt < 4; ++nt)
        bptr[nt] = wp_t + (size_t)(nblk * 128 + wn * 64 + nt * 16 + col16) * 384;

    f32x4 acc[4][4];
#pragma unroll
    for (int i = 0; i < 4; ++i)
#pragma unroll
        for (int j = 0; j < 4; ++j) acc[i][j] = (f32x4){0.f, 0.f, 0.f, 0.f};

    int cur = 0;
    for (int ks = 0; ks < 6; ++ks) {
        __syncthreads();               // buf[cur] ready (vmcnt drained by barrier)
        if (ks < 5) {
            const short* src = asrc + (ks + 1) * (128 * 64);
            for (int i = wv; i < 16; i += 4)
                gload_lds16(src + i * 512 + lane * 8, &At[cur ^ 1][i * 512]);
        }
#pragma unroll
        for (int kk = 0; kk < 2; ++kk) {
            const int kbyte = kk * 64 + kgrp * 16;
            bf16x8 af[4];
#pragma unroll
            for (int mt = 0; mt < 4; ++mt) {
                const int r = wm * 64 + mt * 16 + col16;
                af[mt] = *reinterpret_cast<const bf16x8*>(
                    (const char*)At[cur] + r * 128 + (kbyte ^ ((r & 7) << 4)));
            }
#pragma unroll
            for (int nt = 0; nt < 4; ++nt) {
                bf16x8 bf = *reinterpret_cast<const bf16x8*>(bptr[nt] + ks * 64 + kk * 32 + kgrp * 8);
#pragma unroll
                for (int mt = 0; mt < 4; ++mt)
                    acc[mt][nt] = mfma16(af[mt], bf, acc[mt][nt]);
            }
        }
        cur ^= 1;
    }

    // epilogue: bias + window_reverse scatter
#pragma unroll
    for (int nt = 0; nt < 4; ++nt) {
        int c = nblk * 128 + wn * 64 + nt * 16 + col16;
        float bias = b_proj[c];
#pragma unroll
        for (int mt = 0; mt < 4; ++mt) {
#pragma unroll
            for (int r = 0; r < 4; ++r) {
                int gg = mtile * 128 + wm * 64 + mt * 16 + kgrp * 4 + r;
                int win = gg >> 6, t = gg & 63;
                int b = win >> 6, whr = (win >> 3) & 7, wwc = win & 7;
                int orow = (b * 64 + whr * 8 + (t >> 3)) * 64 + wwc * 8 + (t & 7);
                out[(size_t)orow * 384 + c] = acc[mt][nt][r] + bias;
            }
        }
    }
}

// ================= Path 2 fallback: round-2 fused kernel (scale in prep) ==========
__global__ __launch_bounds__(512, 2)
void win_attn_fused(const float* __restrict__ x, const short* __restrict__ wq_sw,
                    const short* __restrict__ wp_t, const float* __restrict__ b_proj,
                    float* __restrict__ out) {
    __shared__ short Wl[96 * 384];
    __shared__ short q_s[2][64 * 40];
    __shared__ short k_s[2][64 * 40];
    __shared__ short v_t[2][32 * 72];
    __shared__ short ps[2][64 * 72];

    const int tid   = threadIdx.x;
    const int lane  = tid & 63;
    const int wv    = tid >> 6;
    const int col16 = lane & 15;
    const int kgrp  = lane >> 4;
    const int wwin  = wv >> 2;
    const int q4    = wv & 3;
    const int wm    = q4 >> 1, wn = q4 & 1;

    const int win = blockIdx.x * 2 + wwin;
    const int b = win >> 6, wi = win & 63, whr = wi >> 3, wwc = wi & 7;
    const float* xbase = x + (((b * 64) + whr * 8) * 64 + wwc * 8) * 384;

    for (int i = 0; i < 9; ++i) {
        int chunk = wv * 9 + i;
        gload_lds16(wq_sw + chunk * 512 + lane * 8, &Wl[chunk * 512]);
    }
    bf16x8 xf[12];
    {
        int t = q4 * 16 + col16;
        const float* xr = xbase + ((t >> 3) * 64 + (t & 7)) * 384;
#pragma unroll
        for (int kk = 0; kk < 12; ++kk) {
            const float* p0 = xr + kk * 32 + kgrp * 8;
            float4 a = *reinterpret_cast<const float4*>(p0);
            float4 c = *reinterpret_cast<const float4*>(p0 + 4);
            bf16x8 f;
            f[0] = f2bf(a.x); f[1] = f2bf(a.y); f[2] = f2bf(a.z); f[3] = f2bf(a.w);
            f[4] = f2bf(c.x); f[5] = f2bf(c.y); f[6] = f2bf(c.z); f[7] = f2bf(c.w);
            xf[kk] = f;
        }
    }
    f32x4 pacc[2][12];
#pragma unroll
    for (int i = 0; i < 2; ++i)
#pragma unroll
        for (int j = 0; j < 12; ++j) pacc[i][j] = (f32x4){0.f, 0.f, 0.f, 0.f};

    for (int h = 0; h < 12; ++h) {
        __syncthreads();
        f32x4 acc[6];
#pragma unroll
        for (int i = 0; i < 6; ++i) acc[i] = (f32x4){0.f, 0.f, 0.f, 0.f};
#pragma unroll
        for (int kk = 0; kk < 12; ++kk) {
            const int kbyte = (kk * 32 + kgrp * 8) * 2;
#pragma unroll
            for (int rd = 0; rd < 6; ++rd) {
                const int row = (rd >> 1) * 32 + (rd & 1) * 16 + col16;
                const bf16x8 wf = *reinterpret_cast<const bf16x8*>(
                    (const char*)Wl + row * 768 + (kbyte ^ ((row & 7) << 4)));
                if (rd < 4) acc[rd] = mfma16(wf, xf[kk], acc[rd]);
                else        acc[rd] = mfma16(xf[kk], wf, acc[rd]);
            }
        }
#pragma unroll
        for (int rd = 0; rd < 4; ++rd) {
            short* dst = (rd < 2) ? q_s[wwin] : k_s[wwin];
            *reinterpret_cast<short4_t*>(
                &dst[(q4 * 16 + col16) * 40 + (rd & 1) * 16 + kgrp * 4]) = pack4(acc[rd]);
        }
#pragma unroll
        for (int d = 0; d < 2; ++d)
            *reinterpret_cast<short4_t*>(
                &v_t[wwin][(d * 16 + col16) * 72 + q4 * 16 + kgrp * 4]) = pack4(acc[4 + d]);

        __syncthreads();
        if (h < 11) {
            const short* src = wq_sw + (h + 1) * (96 * 384);
            for (int i = 0; i < 9; ++i) {
                int chunk = wv * 9 + i;
                gload_lds16(src + chunk * 512 + lane * 8, &Wl[chunk * 512]);
            }
        }
        bf16x8 qa = *reinterpret_cast<const bf16x8*>(
            &q_s[wwin][(q4 * 16 + col16) * 40 + kgrp * 8]);
        f32x4 sc[4];
#pragma unroll
        for (int nt = 0; nt < 4; ++nt) {
            bf16x8 kf = *reinterpret_cast<const bf16x8*>(
                &k_s[wwin][(nt * 16 + col16) * 40 + kgrp * 8]);
            f32x4 z = (f32x4){0.f, 0.f, 0.f, 0.f};
            sc[nt] = mfma16(qa, kf, z);
        }
        float mx[4], sm[4], p[4][4];
#pragma unroll
        for (int r = 0; r < 4; ++r)
            mx[r] = fmaxf(fmaxf(sc[0][r], sc[1][r]), fmaxf(sc[2][r], sc[3][r]));
#pragma unroll
        for (int d = 1; d < 16; d <<= 1)
#pragma unroll
            for (int r = 0; r < 4; ++r) mx[r] = fmaxf(mx[r], __shfl_xor(mx[r], d, 16));
#pragma unroll
        for (int r = 0; r < 4; ++r) {
            sm[r] = 0.f;
#pragma unroll
            for (int nt = 0; nt < 4; ++nt) { p[nt][r] = __expf(sc[nt][r] - mx[r]); sm[r] += p[nt][r]; }
        }
#pragma unroll
        for (int d = 1; d < 16; d <<= 1)
#pragma unroll
            for (int r = 0; r < 4; ++r) sm[r] += __shfl_xor(sm[r], d, 16);
#pragma unroll
        for (int r = 0; r < 4; ++r) {
            float inv = 1.0f / sm[r];
            int prow = q4 * 16 + kgrp * 4 + r;
#pragma unroll
            for (int nt = 0; nt < 4; ++nt)
                ps[wwin][prow * 72 + nt * 16 + col16] = f2bf(p[nt][r] * inv);
        }
        f32x4 o2[2];
        o2[0] = (f32x4){0.f, 0.f, 0.f, 0.f};
        o2[1] = (f32x4){0.f, 0.f, 0.f, 0.f};
#pragma unroll
        for (int kt = 0; kt < 2; ++kt) {
            bf16x8 pb = *reinterpret_cast<const bf16x8*>(
                &ps[wwin][(q4 * 16 + col16) * 72 + kt * 32 + kgrp * 8]);
#pragma unroll
            for (int d = 0; d < 2; ++d) {
                bf16x8 va = *reinterpret_cast<const bf16x8*>(
                    &v_t[wwin][(d * 16 + col16) * 72 + kt * 32 + kgrp * 8]);
                o2[d] = mfma16(va, pb, o2[d]);
            }
        }
#pragma unroll
        for (int d = 0; d < 2; ++d)
            *reinterpret_cast<short4_t*>(
                &ps[wwin][(q4 * 16 + col16) * 72 + d * 16 + kgrp * 4]) = pack4(o2[d]);
        __syncthreads();
#pragma unroll
        for (int mt = 0; mt < 2; ++mt) {
            bf16x8 ya = *reinterpret_cast<const bf16x8*>(
                &ps[wwin][(wm * 32 + mt * 16 + col16) * 72 + kgrp * 8]);
#pragma unroll
            for (int nt = 0; nt < 12; ++nt) {
                bf16x8 wb = *reinterpret_cast<const bf16x8*>(
                    &wp_t[(wn * 192 + nt * 16 + col16) * 384 + h * 32 + kgrp * 8]);
                pacc[mt][nt] = mfma16(ya, wb, pacc[mt][nt]);
            }
        }
    }
#pragma unroll
    for (int nt = 0; nt < 12; ++nt) {
        int c = wn * 192 + nt * 16 + col16;
        float bias = b_proj[c];
#pragma unroll
        for (int mt = 0; mt < 2; ++mt) {
#pragma unroll
            for (int r = 0; r < 4; ++r) {
                int token = wm * 32 + mt * 16 + kgrp * 4 + r;
                int hh = whr * 8 + (token >> 3);
                int ww2 = wwc * 8 + (token & 7);
                out[(((b * 64) + hh) * 64 + ww2) * 384 + c] = pacc[mt][nt][r] + bias;
            }
        }
    }
}

extern "C" void kernel_launch(void* const* d_in, const int* in_sizes, int n_in,
                              void* d_out, int out_size, void* d_ws, size_t ws_size,
                              hipStream_t stream) {
    const float* x     = (const float*)d_in[0];
    const float* wqkv  = (const float*)d_in[1];
    const float* wproj = (const float*)d_in[2];
    const float* bproj = (const float*)d_in[3];

    short* wq_sw = (short*)d_ws;                  // 884,736 B
    short* wp_t  = wq_sw + 12 * 96 * 384;         // 294,912 B
    short* y_sw  = wp_t + 384 * 384;              // 100,663,296 B (path 1 only)
    const size_t need = (size_t)(12 * 96 * 384 + 384 * 384) * 2 + (size_t)1024 * 6 * 128 * 128;

    prep_weights<<<2304, 256, 0, stream>>>(wqkv, wproj, wq_sw, wp_t);
    if (ws_size >= need) {
        qkv_attn<<<512, 1024, 0, stream>>>(x, wq_sw, y_sw);
        proj_gemm<<<dim3(1024, 3), 256, 0, stream>>>(y_sw, wp_t, bproj, (float*)d_out);
    } else {
        win_attn_fused<<<1024, 512, 0, stream>>>(x, wq_sw, wp_t, bproj, (float*)d_out);
    }
}

// Round 8
// 379.798 us; speedup vs baseline: 1.5903x; 1.0299x over previous
//
#include <hip/hip_runtime.h>

// B=32, H=W=64, C=384, ws=8, heads=12, hd=32; windows=2048, N=64 tokens.
// Path 1 (needs ~102MB d_ws):
//   prep -> qkv_attn (2 win/block, 8 waves, half-staged Wl, 2 blocks/CU,
//                     EXPLICIT vmcnt drains before DMA-consuming barriers)
//        -> proj_gemm (128x128 tiles, window_reverse epilogue)
// Path 2 (fallback, small ws): prep -> win_attn_fused (round-2 kernel)

typedef __attribute__((ext_vector_type(8))) short bf16x8;   // 8 bf16 (4 VGPR) MFMA A/B frag
typedef __attribute__((ext_vector_type(4))) float f32x4;    // MFMA C/D frag
typedef __attribute__((ext_vector_type(4))) short short4_t;

__device__ __forceinline__ short f2bf(float f) {
    union { float f; unsigned u; } v; v.f = f;
    unsigned r = v.u + 0x7fffu + ((v.u >> 16) & 1u);   // RNE
    return (short)(r >> 16);
}

__device__ __forceinline__ unsigned pk2(float a, float b) {   // 2xbf16 dword (a=low)
    return ((unsigned)(unsigned short)f2bf(b) << 16) | (unsigned short)f2bf(a);
}

__device__ __forceinline__ f32x4 mfma16(bf16x8 a, bf16x8 b, f32x4 c) {
    return __builtin_amdgcn_mfma_f32_16x16x32_bf16(a, b, c, 0, 0, 0);
}

__device__ __forceinline__ short4_t pack4(f32x4 v) {
    short4_t s;
    s.x = f2bf(v[0]); s.y = f2bf(v[1]); s.z = f2bf(v[2]); s.w = f2bf(v[3]);
    return s;
}

__device__ __forceinline__ void gload_lds16(const void* g, void* l) {
    __builtin_amdgcn_global_load_lds(
        (const __attribute__((address_space(1))) unsigned int*)g,
        (__attribute__((address_space(3))) unsigned int*)l, 16, 0, 0);
}

// Explicit DMA drain: __syncthreads alone proved insufficient to order
// global_load_lds -> ds_read when the issue->use window is short (r7 race).
__device__ __forceinline__ void drain_vmem() {
    asm volatile("s_waitcnt vmcnt(0)" ::: "memory");
    __builtin_amdgcn_sched_barrier(0);
}

// ---- prep: swizzled per-head QKV weights (Q rows pre-scaled) + transposed proj ----
// wq_sw[h][o]: byte L=2*o holds W_t[row][k], row=L/768, k=((L%768)^((row&7)<<4))/2.
// rows 0..31 = Q dims (x scale), 32..63 = K, 64..95 = V. W_t[row][k]=wqkv[k][col(row,h)].
__global__ void prep_weights(const float* __restrict__ wqkv, const float* __restrict__ wproj,
                             short* __restrict__ wq_sw, short* __restrict__ wp_t) {
    const int QKV_ELEMS = 12 * 96 * 384;
    int i = blockIdx.x * 256 + threadIdx.x;
    if (i < QKV_ELEMS) {
        int h = i / (96 * 384);
        int o = i % (96 * 384);
        int row = o / 384;
        int kb = ((o % 384) * 2) ^ ((row & 7) << 4);
        int k = kb >> 1;
        int col = (row >> 5) * 384 + h * 32 + (row & 31);
        float w = wqkv[k * 1152 + col];
        if (row < 32) w *= 0.17677669529663687f;   // 32^-0.5 folded into Q
        wq_sw[i] = f2bf(w);
    } else if (i < QKV_ELEMS + 384 * 384) {
        int j = i - QKV_ELEMS;
        int n = j / 384, k = j % 384;
        wp_t[j] = f2bf(wproj[k * 384 + n]);
    }
}

// ================= Path 1, kernel A: QKV + attention, y -> ws (swizzled) ==========
// 2 windows/block, 8 waves (512 thr). Wave wid -> (window wid>>2, quad wid&3); each
// wave owns 16 tokens (r4-verified phases). Wl staged in two 48-row halves so
// LDS = 74,752 B -> 2 blocks/CU (barrier-decoupled latency hiding).
__global__ __launch_bounds__(512, 4)
void qkv_attn(const float* __restrict__ x, const short* __restrict__ wq_sw,
              short* __restrict__ y_sw) {
    __shared__ short Wl[48 * 384];       // 36,864 B current 48-row half of W(h)
    __shared__ short k_s[2][64 * 40];    // K [tok][dim]                10,240 B
    __shared__ short v_t[2][32 * 72];    // V^T [dim][tok]               9,216 B
    __shared__ short ps[2][64 * 72];     // P [q][k] (wave-local rows)  18,432 B
    // total 74,752 B -> 2 blocks/CU, 16 waves/CU

    const int tid   = threadIdx.x;
    const int lane  = tid & 63;
    const int wid   = tid >> 6;      // 0..7
    const int col16 = lane & 15;
    const int kgrp  = lane >> 4;     // 0..3
    const int w     = wid >> 2;      // window within block 0..1
    const int quad  = wid & 3;       // quad in window (owns token-tile quad)

    const int win = blockIdx.x * 2 + w;
    const int b = win >> 6, wi = win & 63, whr = wi >> 3, wwc = wi & 7;
    const float* xbase = x + (((b * 64) + whr * 8) * 64 + wwc * 8) * 384;

    // ---- issue DMA of head-0 half-1 (rows 0..47) ----
    for (int i = wid; i < 36; i += 8)
        gload_lds16(wq_sw + i * 512 + lane * 8, &Wl[i * 512]);

    // ---- x token-tile -> registers (48 VGPR) ----
    bf16x8 xf[12];
    {
        int t = quad * 16 + col16;
        const float* xr = xbase + ((t >> 3) * 64 + (t & 7)) * 384;
#pragma unroll
        for (int kk = 0; kk < 12; ++kk) {
            const float* p0 = xr + kk * 32 + kgrp * 8;
            float4 a = *reinterpret_cast<const float4*>(p0);
            float4 c = *reinterpret_cast<const float4*>(p0 + 4);
            bf16x8 f;
            f[0] = f2bf(a.x); f[1] = f2bf(a.y); f[2] = f2bf(a.z); f[3] = f2bf(a.w);
            f[4] = f2bf(c.x); f[5] = f2bf(c.y); f[6] = f2bf(c.z); f[7] = f2bf(c.w);
            xf[kk] = f;
        }
    }

    // y addressing: token g, its A-tile row/mtile (proj GEMM image)
    const int g = win * 64 + quad * 16 + col16;
    const int mtile = g >> 7, yrow = g & 127;
    char* ybase = (char*)y_sw + (size_t)mtile * 98304 + (size_t)yrow * 128;

    for (int h = 0; h < 12; ++h) {
        drain_vmem();      // half1(h) DMA (or prefetch) MUST have landed
        __syncthreads();   // BAR1: half1 visible; k_s/v_t/ps free (prev head done)

        // ---- half1 compute: rows 0..47 = Q d0 (0-15), Q d1 (16-31), K d0 (32-47) ----
        f32x4 aQ0 = (f32x4){0.f, 0.f, 0.f, 0.f};
        f32x4 aQ1 = (f32x4){0.f, 0.f, 0.f, 0.f};
        f32x4 aK0 = (f32x4){0.f, 0.f, 0.f, 0.f};
#pragma unroll
        for (int kk = 0; kk < 12; ++kk) {
            const int kbyte = (kk * 32 + kgrp * 8) * 2;
            const int r0 = col16, r1 = 16 + col16, r2 = 32 + col16;
            bf16x8 wf0 = *reinterpret_cast<const bf16x8*>(
                (const char*)Wl + r0 * 768 + (kbyte ^ ((r0 & 7) << 4)));
            bf16x8 wf1 = *reinterpret_cast<const bf16x8*>(
                (const char*)Wl + r1 * 768 + (kbyte ^ ((r1 & 7) << 4)));
            bf16x8 wf2 = *reinterpret_cast<const bf16x8*>(
                (const char*)Wl + r2 * 768 + (kbyte ^ ((r2 & 7) << 4)));
            aQ0 = mfma16(wf0, xf[kk], aQ0);
            aQ1 = mfma16(wf1, xf[kk], aQ1);
            aK0 = mfma16(wf2, xf[kk], aK0);
        }

        __syncthreads();   // BAR2: all waves done reading half1 -> Wl free

        // ---- issue DMA of half2 (rows 48..95) ----
        {
            const short* src = wq_sw + h * (96 * 384) + 48 * 384;
            for (int i = wid; i < 36; i += 8)
                gload_lds16(src + i * 512 + lane * 8, &Wl[i * 512]);
        }

        // ---- fill the DMA gap: Q relayout (registers) + K-low scatter (k_s only) ----
        // Q relayout D[dim][tok] -> A-frag[tok][dim], in-register (verified r4)
        bf16x8 qa;
        {
            unsigned A0 = pk2(aQ0[0], aQ0[1]);
            unsigned A1 = pk2(aQ0[2], aQ0[3]);
            unsigned B0 = pk2(aQ1[0], aQ1[1]);
            unsigned B1 = pk2(aQ1[2], aQ1[3]);
            int s0 = ((kgrp & 1) * 2) * 16 + col16;
            int a0 = __shfl((int)A0, s0, 64),      a1 = __shfl((int)A1, s0, 64);
            int a2 = __shfl((int)A0, s0 + 16, 64), a3 = __shfl((int)A1, s0 + 16, 64);
            int b0 = __shfl((int)B0, s0, 64),      b1 = __shfl((int)B1, s0, 64);
            int b2 = __shfl((int)B0, s0 + 16, 64), b3 = __shfl((int)B1, s0 + 16, 64);
            union { int i[4]; bf16x8 v; } qu;
            const bool loHalf = (kgrp < 2);
            qu.i[0] = loHalf ? a0 : b0;
            qu.i[1] = loHalf ? a1 : b1;
            qu.i[2] = loHalf ? a2 : b2;
            qu.i[3] = loHalf ? a3 : b3;
            qa = qu.v;
        }
        // K dims 0..15 scatter (b64), stride 40
        *reinterpret_cast<short4_t*>(
            &k_s[w][(quad * 16 + col16) * 40 + kgrp * 4]) = pack4(aK0);

        drain_vmem();      // half2 DMA MUST have landed (short window -> r7 race)
        __syncthreads();   // BAR3: half2 visible (k_s write also ordered)

        // ---- half2 compute: local rows 0..47 = K d1 (48-63), V d0/d1 (64-95) ----
        f32x4 aK1 = (f32x4){0.f, 0.f, 0.f, 0.f};
        f32x4 aV0 = (f32x4){0.f, 0.f, 0.f, 0.f};
        f32x4 aV1 = (f32x4){0.f, 0.f, 0.f, 0.f};
#pragma unroll
        for (int kk = 0; kk < 12; ++kk) {
            const int kbyte = (kk * 32 + kgrp * 8) * 2;
            const int r0 = col16, r1 = 16 + col16, r2 = 32 + col16;  // global&7 == local&7
            bf16x8 wfK = *reinterpret_cast<const bf16x8*>(
                (const char*)Wl + r0 * 768 + (kbyte ^ ((r0 & 7) << 4)));
            bf16x8 wfV0 = *reinterpret_cast<const bf16x8*>(
                (const char*)Wl + r1 * 768 + (kbyte ^ ((r1 & 7) << 4)));
            bf16x8 wfV1 = *reinterpret_cast<const bf16x8*>(
                (const char*)Wl + r2 * 768 + (kbyte ^ ((r2 & 7) << 4)));
            aK1 = mfma16(wfK, xf[kk], aK1);          // D[dim][tok]
            aV0 = mfma16(xf[kk], wfV0, aV0);         // D[tok][dim]
            aV1 = mfma16(xf[kk], wfV1, aV1);
        }
        // K dims 16..31 scatter
        *reinterpret_cast<short4_t*>(
            &k_s[w][(quad * 16 + col16) * 40 + 16 + kgrp * 4]) = pack4(aK1);
        // V scatter: D[tok][dim] -> v_t[dim][tok]
        *reinterpret_cast<short4_t*>(
            &v_t[w][(col16) * 72 + quad * 16 + kgrp * 4]) = pack4(aV0);
        *reinterpret_cast<short4_t*>(
            &v_t[w][(16 + col16) * 72 + quad * 16 + kgrp * 4]) = pack4(aV1);

        __syncthreads();   // BAR4: K/V complete; half2 consumed -> Wl free for next DMA

        // ---- prefetch next head's half1 (hides under scores/softmax/PV) ----
        if (h < 11) {
            const short* src = wq_sw + (h + 1) * (96 * 384);
            for (int i = wid; i < 36; i += 8)
                gload_lds16(src + i * 512 + lane * 8, &Wl[i * 512]);
        }

        // ---- scores: wave owns q-rows quad*16..+15 ----
        f32x4 sc[4];
#pragma unroll
        for (int nt = 0; nt < 4; ++nt) {
            bf16x8 kf = *reinterpret_cast<const bf16x8*>(
                &k_s[w][(nt * 16 + col16) * 40 + kgrp * 8]);
            f32x4 z = (f32x4){0.f, 0.f, 0.f, 0.f};
            sc[nt] = mfma16(qa, kf, z);
        }
        // ---- softmax (4 independent row-chains) ----
        float mx[4], sm[4];
#pragma unroll
        for (int r = 0; r < 4; ++r)
            mx[r] = fmaxf(fmaxf(sc[0][r], sc[1][r]), fmaxf(sc[2][r], sc[3][r]));
#pragma unroll
        for (int d = 1; d < 16; d <<= 1)
#pragma unroll
            for (int r = 0; r < 4; ++r) mx[r] = fmaxf(mx[r], __shfl_xor(mx[r], d, 16));
#pragma unroll
        for (int r = 0; r < 4; ++r) {
            sm[r] = 0.f;
#pragma unroll
            for (int nt = 0; nt < 4; ++nt) {
                sc[nt][r] = __expf(sc[nt][r] - mx[r]); sm[r] += sc[nt][r];
            }
        }
#pragma unroll
        for (int d = 1; d < 16; d <<= 1)
#pragma unroll
            for (int r = 0; r < 4; ++r) sm[r] += __shfl_xor(sm[r], d, 16);
#pragma unroll
        for (int r = 0; r < 4; ++r) {
            float inv = 1.0f / sm[r];
            int prow = quad * 16 + kgrp * 4 + r;
#pragma unroll
            for (int nt = 0; nt < 4; ++nt)
                ps[w][prow * 72 + nt * 16 + col16] = f2bf(sc[nt][r] * inv);
        }
        // ---- PV via mfma(V^T, P) -> D[dim][q]; wave-local ps rows, no barrier ----
        f32x4 o2[2];
        o2[0] = (f32x4){0.f, 0.f, 0.f, 0.f};
        o2[1] = (f32x4){0.f, 0.f, 0.f, 0.f};
#pragma unroll
        for (int kt = 0; kt < 2; ++kt) {
            bf16x8 pb = *reinterpret_cast<const bf16x8*>(
                &ps[w][(quad * 16 + col16) * 72 + kt * 32 + kgrp * 8]);
#pragma unroll
            for (int d = 0; d < 2; ++d) {
                bf16x8 va = *reinterpret_cast<const bf16x8*>(
                    &v_t[w][(d * 16 + col16) * 72 + kt * 32 + kgrp * 8]);
                o2[d] = mfma16(va, pb, o2[d]);
            }
        }
        // ---- y write (swizzled proj-A image): token=col16-row, dims kgrp*4..+3 ----
#pragma unroll
        for (int d = 0; d < 2; ++d) {
            int c0 = h * 32 + d * 16 + kgrp * 4;
            int kchunk = c0 >> 6;
            int koff = (2 * (c0 & 63)) ^ ((yrow & 7) << 4);
            *reinterpret_cast<short4_t*>(ybase + kchunk * 16384 + koff) = pack4(o2[d]);
        }
    }
}

// ================= Path 1, kernel B: out = y @ wp + bias, window_reverse ==========
__global__ __launch_bounds__(256)
void proj_gemm(const short* __restrict__ y_sw, const short* __restrict__ wp_t,
               const float* __restrict__ b_proj, float* __restrict__ out) {
    __shared__ short At[2][128 * 64];   // 2 x 16 KiB swizzled A tiles

    const int tid = threadIdx.x, lane = tid & 63, wv = tid >> 6;
    const int col16 = lane & 15, kgrp = lane >> 4;
    const int wm = wv >> 1, wn = wv & 1;
    const int mtile = blockIdx.x;       // 0..1023
    const int nblk  = blockIdx.y;       // 0..2

    const short* asrc = y_sw + (size_t)mtile * 6 * 128 * 64;

    // prologue: stage kchunk 0
    for (int i = wv; i < 16; i += 4)
        gload_lds16(asrc + i * 512 + lane * 8, &At[0][i * 512]);

    const short* bptr[4];
#pragma unroll
    for (int nt = 0; nt < 4; ++nt)
        bptr[nt] = wp_t + (size_t)(nblk * 128 + wn * 64 + nt * 16 + col16) * 384;

    f32x4 acc[4][4];
#pragma unroll
    for (int i = 0; i < 4; ++i)
#pragma unroll
        for (int j = 0; j < 4; ++j) acc[i][j] = (f32x4){0.f, 0.f, 0.f, 0.f};

    int cur = 0;
    for (int ks = 0; ks < 6; ++ks) {
        drain_vmem();                  // buf[cur]'s DMA must have landed
        __syncthreads();
        if (ks < 5) {
            const short* src = asrc + (ks + 1) * (128 * 64);
            for (int i = wv; i < 16; i += 4)
                gload_lds16(src + i * 512 + lane * 8, &At[cur ^ 1][i * 512]);
        }
#pragma unroll
        for (int kk = 0; kk < 2; ++kk) {
            const int kbyte = kk * 64 + kgrp * 16;
            bf16x8 af[4];
#pragma unroll
            for (int mt = 0; mt < 4; ++mt) {
                const int r = wm * 64 + mt * 16 + col16;
                af[mt] = *reinterpret_cast<const bf16x8*>(
                    (const char*)At[cur] + r * 128 + (kbyte ^ ((r & 7) << 4)));
            }
#pragma unroll
            for (int nt = 0; nt < 4; ++nt) {
                bf16x8 bf = *reinterpret_cast<const bf16x8*>(bptr[nt] + ks * 64 + kk * 32 + kgrp * 8);
#pragma unroll
                for (int mt = 0; mt < 4; ++mt)
                    acc[mt][nt] = mfma16(af[mt], bf, acc[mt][nt]);
            }
        }
        cur ^= 1;
    }

    // epilogue: bias + window_reverse scatter
#pragma unroll
    for (int nt = 0; nt < 4; ++nt) {
        int c = nblk * 128 + wn * 64 + nt * 16 + col16;
        float bias = b_proj[c];
#pragma unroll
        for (int mt = 0; mt < 4; ++mt) {
#pragma unroll
            for (int r = 0; r < 4; ++r) {
                int gg = mtile * 128 + wm * 64 + mt * 16 + kgrp * 4 + r;
                int win = gg >> 6, t = gg & 63;
                int b = win >> 6, whr = (win >> 3) & 7, wwc = win & 7;
                int orow = (b * 64 + whr * 8 + (t >> 3)) * 64 + wwc * 8 + (t & 7);
                out[(size_t)orow * 384 + c] = acc[mt][nt][r] + bias;
            }
        }
    }
}

// ================= Path 2 fallback: round-2 fused kernel (scale in prep) ==========
__global__ __launch_bounds__(512, 2)
void win_attn_fused(const float* __restrict__ x, const short* __restrict__ wq_sw,
                    const short* __restrict__ wp_t, const float* __restrict__ b_proj,
                    float* __restrict__ out) {
    __shared__ short Wl[96 * 384];
    __shared__ short q_s[2][64 * 40];
    __shared__ short k_s[2][64 * 40];
    __shared__ short v_t[2][32 * 72];
    __shared__ short ps[2][64 * 72];

    const int tid   = threadIdx.x;
    const int lane  = tid & 63;
    const int wv    = tid >> 6;
    const int col16 = lane & 15;
    const int kgrp  = lane >> 4;
    const int wwin  = wv >> 2;
    const int q4    = wv & 3;
    const int wm    = q4 >> 1, wn = q4 & 1;

    const int win = blockIdx.x * 2 + wwin;
    const int b = win >> 6, wi = win & 63, whr = wi >> 3, wwc = wi & 7;
    const float* xbase = x + (((b * 64) + whr * 8) * 64 + wwc * 8) * 384;

    for (int i = 0; i < 9; ++i) {
        int chunk = wv * 9 + i;
        gload_lds16(wq_sw + chunk * 512 + lane * 8, &Wl[chunk * 512]);
    }
    bf16x8 xf[12];
    {
        int t = q4 * 16 + col16;
        const float* xr = xbase + ((t >> 3) * 64 + (t & 7)) * 384;
#pragma unroll
        for (int kk = 0; kk < 12; ++kk) {
            const float* p0 = xr + kk * 32 + kgrp * 8;
            float4 a = *reinterpret_cast<const float4*>(p0);
            float4 c = *reinterpret_cast<const float4*>(p0 + 4);
            bf16x8 f;
            f[0] = f2bf(a.x); f[1] = f2bf(a.y); f[2] = f2bf(a.z); f[3] = f2bf(a.w);
            f[4] = f2bf(c.x); f[5] = f2bf(c.y); f[6] = f2bf(c.z); f[7] = f2bf(c.w);
            xf[kk] = f;
        }
    }
    f32x4 pacc[2][12];
#pragma unroll
    for (int i = 0; i < 2; ++i)
#pragma unroll
        for (int j = 0; j < 12; ++j) pacc[i][j] = (f32x4){0.f, 0.f, 0.f, 0.f};

    for (int h = 0; h < 12; ++h) {
        drain_vmem();
        __syncthreads();
        f32x4 acc[6];
#pragma unroll
        for (int i = 0; i < 6; ++i) acc[i] = (f32x4){0.f, 0.f, 0.f, 0.f};
#pragma unroll
        for (int kk = 0; kk < 12; ++kk) {
            const int kbyte = (kk * 32 + kgrp * 8) * 2;
#pragma unroll
            for (int rd = 0; rd < 6; ++rd) {
                const int row = (rd >> 1) * 32 + (rd & 1) * 16 + col16;
                const bf16x8 wf = *reinterpret_cast<const bf16x8*>(
                    (const char*)Wl + row * 768 + (kbyte ^ ((row & 7) << 4)));
                if (rd < 4) acc[rd] = mfma16(wf, xf[kk], acc[rd]);
                else        acc[rd] = mfma16(xf[kk], wf, acc[rd]);
            }
        }
#pragma unroll
        for (int rd = 0; rd < 4; ++rd) {
            short* dst = (rd < 2) ? q_s[wwin] : k_s[wwin];
            *reinterpret_cast<short4_t*>(
                &dst[(q4 * 16 + col16) * 40 + (rd & 1) * 16 + kgrp * 4]) = pack4(acc[rd]);
        }
#pragma unroll
        for (int d = 0; d < 2; ++d)
            *reinterpret_cast<short4_t*>(
                &v_t[wwin][(d * 16 + col16) * 72 + q4 * 16 + kgrp * 4]) = pack4(acc[4 + d]);

        __syncthreads();
        if (h < 11) {
            const short* src = wq_sw + (h + 1) * (96 * 384);
            for (int i = 0; i < 9; ++i) {
                int chunk = wv * 9 + i;
                gload_lds16(src + chunk * 512 + lane * 8, &Wl[chunk * 512]);
            }
        }
        bf16x8 qa = *reinterpret_cast<const bf16x8*>(
            &q_s[wwin][(q4 * 16 + col16) * 40 + kgrp * 8]);
        f32x4 sc[4];
#pragma unroll
        for (int nt = 0; nt < 4; ++nt) {
            bf16x8 kf = *reinterpret_cast<const bf16x8*>(
                &k_s[wwin][(nt * 16 + col16) * 40 + kgrp * 8]);
            f32x4 z = (f32x4){0.f, 0.f, 0.f, 0.f};
            sc[nt] = mfma16(qa, kf, z);
        }
        float mx[4], sm[4], p[4][4];
#pragma unroll
        for (int r = 0; r < 4; ++r)
            mx[r] = fmaxf(fmaxf(sc[0][r], sc[1][r]), fmaxf(sc[2][r], sc[3][r]));
#pragma unroll
        for (int d = 1; d < 16; d <<= 1)
#pragma unroll
            for (int r = 0; r < 4; ++r) mx[r] = fmaxf(mx[r], __shfl_xor(mx[r], d, 16));
#pragma unroll
        for (int r = 0; r < 4; ++r) {
            sm[r] = 0.f;
#pragma unroll
            for (int nt = 0; nt < 4; ++nt) { p[nt][r] = __expf(sc[nt][r] - mx[r]); sm[r] += p[nt][r]; }
        }
#pragma unroll
        for (int d = 1; d < 16; d <<= 1)
#pragma unroll
            for (int r = 0; r < 4; ++r) sm[r] += __shfl_xor(sm[r], d, 16);
#pragma unroll
        for (int r = 0; r < 4; ++r) {
            float inv = 1.0f / sm[r];
            int prow = q4 * 16 + kgrp * 4 + r;
#pragma unroll
            for (int nt = 0; nt < 4; ++nt)
                ps[wwin][prow * 72 + nt * 16 + col16] = f2bf(p[nt][r] * inv);
        }
        f32x4 o2[2];
        o2[0] = (f32x4){0.f, 0.f, 0.f, 0.f};
        o2[1] = (f32x4){0.f, 0.f, 0.f, 0.f};
#pragma unroll
        for (int kt = 0; kt < 2; ++kt) {
            bf16x8 pb = *reinterpret_cast<const bf16x8*>(
                &ps[wwin][(q4 * 16 + col16) * 72 + kt * 32 + kgrp * 8]);
#pragma unroll
            for (int d = 0; d < 2; ++d) {
                bf16x8 va = *reinterpret_cast<const bf16x8*>(
                    &v_t[wwin][(d * 16 + col16) * 72 + kt * 32 + kgrp * 8]);
                o2[d] = mfma16(va, pb, o2[d]);
            }
        }
#pragma unroll
        for (int d = 0; d < 2; ++d)
            *reinterpret_cast<short4_t*>(
                &ps[wwin][(q4 * 16 + col16) * 72 + d * 16 + kgrp * 4]) = pack4(o2[d]);
        __syncthreads();
#pragma unroll
        for (int mt = 0; mt < 2; ++mt) {
            bf16x8 ya = *reinterpret_cast<const bf16x8*>(
                &ps[wwin][(wm * 32 + mt * 16 + col16) * 72 + kgrp * 8]);
#pragma unroll
            for (int nt = 0; nt < 12; ++nt) {
                bf16x8 wb = *reinterpret_cast<const bf16x8*>(
                    &wp_t[(wn * 192 + nt * 16 + col16) * 384 + h * 32 + kgrp * 8]);
                pacc[mt][nt] = mfma16(ya, wb, pacc[mt][nt]);
            }
        }
    }
#pragma unroll
    for (int nt = 0; nt < 12; ++nt) {
        int c = wn * 192 + nt * 16 + col16;
        float bias = b_proj[c];
#pragma unroll
        for (int mt = 0; mt < 2; ++mt) {
#pragma unroll
            for (int r = 0; r < 4; ++r) {
                int token = wm * 32 + mt * 16 + kgrp * 4 + r;
                int hh = whr * 8 + (token >> 3);
                int ww2 = wwc * 8 + (token & 7);
                out[(((b * 64) + hh) * 64 + ww2) * 384 + c] = pacc[mt][nt][r] + bias;
            }
        }
    }
}

extern "C" void kernel_launch(void* const* d_in, const int* in_sizes, int n_in,
                              void* d_out, int out_size, void* d_ws, size_t ws_size,
                              hipStream_t stream) {
    const float* x     = (const float*)d_in[0];
    const float* wqkv  = (const float*)d_in[1];
    const float* wproj = (const float*)d_in[2];
    const float* bproj = (const float*)d_in[3];

    short* wq_sw = (short*)d_ws;                  // 884,736 B
    short* wp_t  = wq_sw + 12 * 96 * 384;         // 294,912 B
    short* y_sw  = wp_t + 384 * 384;              // 100,663,296 B (path 1 only)
    const size_t need = (size_t)(12 * 96 * 384 + 384 * 384) * 2 + (size_t)1024 * 6 * 128 * 128;

    prep_weights<<<2304, 256, 0, stream>>>(wqkv, wproj, wq_sw, wp_t);
    if (ws_size >= need) {
        qkv_attn<<<1024, 512, 0, stream>>>(x, wq_sw, y_sw);
        proj_gemm<<<dim3(1024, 3), 256, 0, stream>>>(y_sw, wp_t, bproj, (float*)d_out);
    } else {
        win_attn_fused<<<1024, 512, 0, stream>>>(x, wq_sw, wp_t, bproj, (float*)d_out);
    }
}

// Round 9
// 318.309 us; speedup vs baseline: 1.8975x; 1.1932x over previous
//
#include <hip/hip_runtime.h>

// B=32, H=W=64, C=384, ws=8, heads=12, hd=32; windows=2048, N=64 tokens.
// Path 1 (needs ~102MB d_ws):
//   prep -> qkv_attn (2 win/block, 8 waves, half-staged fragment-major Wl,
//                     2 blocks/CU, swapped-scores in-lane softmax)
//        -> proj_gemm (128x128 tiles, window_reverse epilogue)
// Path 2 (fallback, small ws): prep -> win_attn_fused
//
// W LDS layout (fragment-major, per 48-row half): 16B frag of rows' k-slice at
//   byte ((g*12 + kk)*48 + row)*16,  g=kgrp 0..3, kk=0..11 (K-block of 32), row 0..47.
// -> per-lane base computed once; reads use immediate offsets; provably conflict-free.

typedef __attribute__((ext_vector_type(8))) short bf16x8;   // 8 bf16 (4 VGPR) MFMA A/B frag
typedef __attribute__((ext_vector_type(4))) float f32x4;    // MFMA C/D frag
typedef __attribute__((ext_vector_type(4))) short short4_t;

__device__ __forceinline__ short f2bf(float f) {
    union { float f; unsigned u; } v; v.f = f;
    unsigned r = v.u + 0x7fffu + ((v.u >> 16) & 1u);   // RNE
    return (short)(r >> 16);
}

__device__ __forceinline__ unsigned pk2(float a, float b) {   // 2xbf16 dword (a=low)
    return ((unsigned)(unsigned short)f2bf(b) << 16) | (unsigned short)f2bf(a);
}

__device__ __forceinline__ f32x4 mfma16(bf16x8 a, bf16x8 b, f32x4 c) {
    return __builtin_amdgcn_mfma_f32_16x16x32_bf16(a, b, c, 0, 0, 0);
}

__device__ __forceinline__ short4_t pack4(f32x4 v) {
    short4_t s;
    s.x = f2bf(v[0]); s.y = f2bf(v[1]); s.z = f2bf(v[2]); s.w = f2bf(v[3]);
    return s;
}

__device__ __forceinline__ void gload_lds16(const void* g, void* l) {
    __builtin_amdgcn_global_load_lds(
        (const __attribute__((address_space(1))) unsigned int*)g,
        (__attribute__((address_space(3))) unsigned int*)l, 16, 0, 0);
}

// Explicit DMA drain: __syncthreads alone proved insufficient to order
// global_load_lds -> ds_read when the issue->use window is short (r7 race).
__device__ __forceinline__ void drain_vmem() {
    asm volatile("s_waitcnt vmcnt(0)" ::: "memory");
    __builtin_amdgcn_sched_barrier(0);
}

// ---- prep: fragment-major per-head QKV weights (Q rows pre-scaled) + wp^T ----
// wq_fm element idx = ((((h*2 + half)*4 + g)*12 + kk)*48 + row)*8 + e
//   grow = half*48+row: 0..31 = Q dims (x scale), 32..63 = K, 64..95 = V.
//   value = wqkv[k][col], k = kk*32 + g*8 + e, col = (grow>>5)*384 + h*32 + (grow&31).
__global__ void prep_weights(const float* __restrict__ wqkv, const float* __restrict__ wproj,
                             short* __restrict__ wq_fm, short* __restrict__ wp_t) {
    const int QKV_ELEMS = 12 * 96 * 384;
    int i = blockIdx.x * 256 + threadIdx.x;
    if (i < QKV_ELEMS) {
        int e    = i & 7;
        int f    = i >> 3;
        int row  = f % 48;
        int kk   = (f / 48) % 12;
        int g    = (f / (48 * 12)) % 4;
        int half = (f / (48 * 12 * 4)) & 1;
        int h    = f / (48 * 12 * 4 * 2);
        int grow = half * 48 + row;
        int k    = kk * 32 + g * 8 + e;
        int col  = (grow >> 5) * 384 + h * 32 + (grow & 31);
        float w = wqkv[k * 1152 + col];
        if (grow < 32) w *= 0.17677669529663687f;   // 32^-0.5 folded into Q
        wq_fm[i] = f2bf(w);
    } else if (i < QKV_ELEMS + 384 * 384) {
        int j = i - QKV_ELEMS;
        int n = j / 384, k = j % 384;
        wp_t[j] = f2bf(wproj[k * 384 + n]);
    }
}

// ================= Path 1, kernel A: QKV + attention, y -> ws (swizzled) ==========
__global__ __launch_bounds__(512, 4)
void qkv_attn(const float* __restrict__ x, const short* __restrict__ wq_fm,
              short* __restrict__ y_sw) {
    __shared__ short Wl[48 * 384];       // 36,864 B current 48-row half (fragment-major)
    __shared__ short k_s[2][64 * 40];    // K [tok][dim]                10,240 B
    __shared__ short v_t[2][32 * 72];    // V^T [dim][tok]               9,216 B
    __shared__ short ps[2][64 * 72];     // P [q][k] (wave-local rows)  18,432 B
    // total 74,752 B -> 2 blocks/CU, 16 waves/CU

    const int tid   = threadIdx.x;
    const int lane  = tid & 63;
    const int wid   = tid >> 6;      // 0..7
    const int col16 = lane & 15;
    const int kgrp  = lane >> 4;     // 0..3
    const int w     = wid >> 2;      // window within block 0..1
    const int quad  = wid & 3;       // quad in window (owns token-tile quad)

    const int win = blockIdx.x * 2 + w;
    const int b = win >> 6, wi = win & 63, whr = wi >> 3, wwc = wi & 7;
    const float* xbase = x + (((b * 64) + whr * 8) * 64 + wwc * 8) * 384;

    // per-lane W base (fragment-major): frag(g,kk,row=mt*16+c) at base + kk*768 + mt*256
    const char* Wb = (const char*)Wl + kgrp * 9216 + col16 * 16;

    // ---- issue DMA of head-0 half-1 ----
    for (int i = wid; i < 36; i += 8)
        gload_lds16(wq_fm + i * 512 + lane * 8, &Wl[i * 512]);

    // ---- x token-tile -> registers (48 VGPR) ----
    bf16x8 xf[12];
    {
        int t = quad * 16 + col16;
        const float* xr = xbase + ((t >> 3) * 64 + (t & 7)) * 384;
#pragma unroll
        for (int kk = 0; kk < 12; ++kk) {
            const float* p0 = xr + kk * 32 + kgrp * 8;
            float4 a = *reinterpret_cast<const float4*>(p0);
            float4 c = *reinterpret_cast<const float4*>(p0 + 4);
            bf16x8 f;
            f[0] = f2bf(a.x); f[1] = f2bf(a.y); f[2] = f2bf(a.z); f[3] = f2bf(a.w);
            f[4] = f2bf(c.x); f[5] = f2bf(c.y); f[6] = f2bf(c.z); f[7] = f2bf(c.w);
            xf[kk] = f;
        }
    }

    // y addressing: token g, its A-tile row/mtile (proj GEMM image)
    const int g = win * 64 + quad * 16 + col16;
    const int mtile = g >> 7, yrow = g & 127;
    char* ybase = (char*)y_sw + (size_t)mtile * 98304 + (size_t)yrow * 128;

    for (int h = 0; h < 12; ++h) {
        drain_vmem();      // half1(h) DMA (or prefetch) MUST have landed
        __syncthreads();   // BAR1: half1 visible; k_s/v_t/ps free (prev head done)

        // ---- half1: local rows 0-15 = Q d0, 16-31 = Q d1, 32-47 = K d0 ----
        f32x4 aQ0 = (f32x4){0.f, 0.f, 0.f, 0.f};
        f32x4 aQ1 = (f32x4){0.f, 0.f, 0.f, 0.f};
        f32x4 aK0 = (f32x4){0.f, 0.f, 0.f, 0.f};
#pragma unroll
        for (int kk = 0; kk < 12; ++kk) {
            bf16x8 wf0 = *reinterpret_cast<const bf16x8*>(Wb + kk * 768);
            bf16x8 wf1 = *reinterpret_cast<const bf16x8*>(Wb + kk * 768 + 256);
            bf16x8 wf2 = *reinterpret_cast<const bf16x8*>(Wb + kk * 768 + 512);
            aQ0 = mfma16(wf0, xf[kk], aQ0);
            aQ1 = mfma16(wf1, xf[kk], aQ1);
            aK0 = mfma16(wf2, xf[kk], aK0);
        }

        __syncthreads();   // BAR2: all waves done reading half1 -> Wl free

        // ---- issue DMA of half2 ----
        {
            const short* src = wq_fm + h * 36864 + 18432;
            for (int i = wid; i < 36; i += 8)
                gload_lds16(src + i * 512 + lane * 8, &Wl[i * 512]);
        }

        // ---- fill the DMA gap: Q relayout (registers) + K-low scatter ----
        // Q relayout D[dim][tok] -> frag[tok][dim] (A-layout == B-layout transposed)
        bf16x8 qa;
        {
            unsigned A0 = pk2(aQ0[0], aQ0[1]);
            unsigned A1 = pk2(aQ0[2], aQ0[3]);
            unsigned B0 = pk2(aQ1[0], aQ1[1]);
            unsigned B1 = pk2(aQ1[2], aQ1[3]);
            int s0 = ((kgrp & 1) * 2) * 16 + col16;
            int a0 = __shfl((int)A0, s0, 64),      a1 = __shfl((int)A1, s0, 64);
            int a2 = __shfl((int)A0, s0 + 16, 64), a3 = __shfl((int)A1, s0 + 16, 64);
            int b0 = __shfl((int)B0, s0, 64),      b1 = __shfl((int)B1, s0, 64);
            int b2 = __shfl((int)B0, s0 + 16, 64), b3 = __shfl((int)B1, s0 + 16, 64);
            union { int i[4]; bf16x8 v; } qu;
            const bool loHalf = (kgrp < 2);
            qu.i[0] = loHalf ? a0 : b0;
            qu.i[1] = loHalf ? a1 : b1;
            qu.i[2] = loHalf ? a2 : b2;
            qu.i[3] = loHalf ? a3 : b3;
            qa = qu.v;
        }
        // K dims 0..15 scatter (b64), stride 40
        *reinterpret_cast<short4_t*>(
            &k_s[w][(quad * 16 + col16) * 40 + kgrp * 4]) = pack4(aK0);

        drain_vmem();      // half2 DMA MUST have landed (short window -> r7 race)
        __syncthreads();   // BAR3: half2 visible (k_s write also ordered)

        // ---- half2: local rows 0-15 = K d1, 16-31 = V d0, 32-47 = V d1 ----
        f32x4 aK1 = (f32x4){0.f, 0.f, 0.f, 0.f};
        f32x4 aV0 = (f32x4){0.f, 0.f, 0.f, 0.f};
        f32x4 aV1 = (f32x4){0.f, 0.f, 0.f, 0.f};
#pragma unroll
        for (int kk = 0; kk < 12; ++kk) {
            bf16x8 wfK  = *reinterpret_cast<const bf16x8*>(Wb + kk * 768);
            bf16x8 wfV0 = *reinterpret_cast<const bf16x8*>(Wb + kk * 768 + 256);
            bf16x8 wfV1 = *reinterpret_cast<const bf16x8*>(Wb + kk * 768 + 512);
            aK1 = mfma16(wfK, xf[kk], aK1);          // D[dim][tok]
            aV0 = mfma16(xf[kk], wfV0, aV0);         // D[tok][dim]
            aV1 = mfma16(xf[kk], wfV1, aV1);
        }
        // K dims 16..31 scatter
        *reinterpret_cast<short4_t*>(
            &k_s[w][(quad * 16 + col16) * 40 + 16 + kgrp * 4]) = pack4(aK1);
        // V scatter: D[tok][dim] -> v_t[dim][tok]
        *reinterpret_cast<short4_t*>(
            &v_t[w][(col16) * 72 + quad * 16 + kgrp * 4]) = pack4(aV0);
        *reinterpret_cast<short4_t*>(
            &v_t[w][(16 + col16) * 72 + quad * 16 + kgrp * 4]) = pack4(aV1);

        __syncthreads();   // BAR4: K/V complete; half2 consumed -> Wl free for next DMA

        // ---- prefetch next head's half1 (hides under scores/softmax/PV) ----
        if (h < 11) {
            const short* src = wq_fm + (h + 1) * 36864;
            for (int i = wid; i < 36; i += 8)
                gload_lds16(src + i * 512 + lane * 8, &Wl[i * 512]);
        }

        // ---- scores SWAPPED: D[k-tok][q-tok] = mfma(K_frag, Q_frag) ----
        // lane (c,g): sc[nt][r] = S[q = quad*16+c][k = nt*16 + g*4 + r]
        f32x4 sc[4];
#pragma unroll
        for (int nt = 0; nt < 4; ++nt) {
            bf16x8 kf = *reinterpret_cast<const bf16x8*>(
                &k_s[w][(nt * 16 + col16) * 40 + kgrp * 8]);
            f32x4 z = (f32x4){0.f, 0.f, 0.f, 0.f};
            sc[nt] = mfma16(kf, qa, z);
        }
        // ---- softmax: q-row is lane-local (16 vals) + 2 cross-lane steps ----
        float m = sc[0][0];
#pragma unroll
        for (int nt = 0; nt < 4; ++nt)
#pragma unroll
            for (int r = 0; r < 4; ++r) m = fmaxf(m, sc[nt][r]);
        m = fmaxf(m, __shfl_xor(m, 16, 64));
        m = fmaxf(m, __shfl_xor(m, 32, 64));
        float s = 0.f;
#pragma unroll
        for (int nt = 0; nt < 4; ++nt)
#pragma unroll
            for (int r = 0; r < 4; ++r) {
                sc[nt][r] = __expf(sc[nt][r] - m);
                s += sc[nt][r];
            }
        s += __shfl_xor(s, 16, 64);
        s += __shfl_xor(s, 32, 64);
        float inv = 1.0f / s;
        // P store: lane writes its 4x short4 runs P[q=quad*16+c][nt*16 + g*4 .. +3]
#pragma unroll
        for (int nt = 0; nt < 4; ++nt) {
            f32x4 pv;
            pv[0] = sc[nt][0] * inv; pv[1] = sc[nt][1] * inv;
            pv[2] = sc[nt][2] * inv; pv[3] = sc[nt][3] * inv;
            *reinterpret_cast<short4_t*>(
                &ps[w][(quad * 16 + col16) * 72 + nt * 16 + kgrp * 4]) = pack4(pv);
        }
        // ---- PV via mfma(V^T, P) -> D[dim][q]; wave-local ps rows, no barrier ----
        f32x4 o2[2];
        o2[0] = (f32x4){0.f, 0.f, 0.f, 0.f};
        o2[1] = (f32x4){0.f, 0.f, 0.f, 0.f};
#pragma unroll
        for (int kt = 0; kt < 2; ++kt) {
            bf16x8 pb = *reinterpret_cast<const bf16x8*>(
                &ps[w][(quad * 16 + col16) * 72 + kt * 32 + kgrp * 8]);
#pragma unroll
            for (int d = 0; d < 2; ++d) {
                bf16x8 va = *reinterpret_cast<const bf16x8*>(
                    &v_t[w][(d * 16 + col16) * 72 + kt * 32 + kgrp * 8]);
                o2[d] = mfma16(va, pb, o2[d]);
            }
        }
        // ---- y write (swizzled proj-A image): token=col16-row, dims kgrp*4..+3 ----
#pragma unroll
        for (int d = 0; d < 2; ++d) {
            int c0 = h * 32 + d * 16 + kgrp * 4;
            int kchunk = c0 >> 6;
            int koff = (2 * (c0 & 63)) ^ ((yrow & 7) << 4);
            *reinterpret_cast<short4_t*>(ybase + kchunk * 16384 + koff) = pack4(o2[d]);
        }
    }
}

// ================= Path 1, kernel B: out = y @ wp + bias, window_reverse ==========
__global__ __launch_bounds__(256)
void proj_gemm(const short* __restrict__ y_sw, const short* __restrict__ wp_t,
               const float* __restrict__ b_proj, float* __restrict__ out) {
    __shared__ short At[2][128 * 64];   // 2 x 16 KiB swizzled A tiles

    const int tid = threadIdx.x, lane = tid & 63, wv = tid >> 6;
    const int col16 = lane & 15, kgrp = lane >> 4;
    const int wm = wv >> 1, wn = wv & 1;
    const int mtile = blockIdx.x;       // 0..1023
    const int nblk  = blockIdx.y;       // 0..2

    const short* asrc = y_sw + (size_t)mtile * 6 * 128 * 64;

    // prologue: stage kchunk 0
    for (int i = wv; i < 16; i += 4)
        gload_lds16(asrc + i * 512 + lane * 8, &At[0][i * 512]);

    const short* bptr[4];
#pragma unroll
    for (int nt = 0; nt < 4; ++nt)
        bptr[nt] = wp_t + (size_t)(nblk * 128 + wn * 64 + nt * 16 + col16) * 384;

    f32x4 acc[4][4];
#pragma unroll
    for (int i = 0; i < 4; ++i)
#pragma unroll
        for (int j = 0; j < 4; ++j) acc[i][j] = (f32x4){0.f, 0.f, 0.f, 0.f};

    int cur = 0;
    for (int ks = 0; ks < 6; ++ks) {
        drain_vmem();                  // buf[cur]'s DMA must have landed
        __syncthreads();
        if (ks < 5) {
            const short* src = asrc + (ks + 1) * (128 * 64);
            for (int i = wv; i < 16; i += 4)
                gload_lds16(src + i * 512 + lane * 8, &At[cur ^ 1][i * 512]);
        }
#pragma unroll
        for (int kk = 0; kk < 2; ++kk) {
            const int kbyte = kk * 64 + kgrp * 16;
            bf16x8 af[4];
#pragma unroll
            for (int mt = 0; mt < 4; ++mt) {
                const int r = wm * 64 + mt * 16 + col16;
                af[mt] = *reinterpret_cast<const bf16x8*>(
                    (const char*)At[cur] + r * 128 + (kbyte ^ ((r & 7) << 4)));
            }
#pragma unroll
            for (int nt = 0; nt < 4; ++nt) {
                bf16x8 bf = *reinterpret_cast<const bf16x8*>(bptr[nt] + ks * 64 + kk * 32 + kgrp * 8);
#pragma unroll
                for (int mt = 0; mt < 4; ++mt)
                    acc[mt][nt] = mfma16(af[mt], bf, acc[mt][nt]);
            }
        }
        cur ^= 1;
    }

    // epilogue: bias + window_reverse scatter
#pragma unroll
    for (int nt = 0; nt < 4; ++nt) {
        int c = nblk * 128 + wn * 64 + nt * 16 + col16;
        float bias = b_proj[c];
#pragma unroll
        for (int mt = 0; mt < 4; ++mt) {
#pragma unroll
            for (int r = 0; r < 4; ++r) {
                int gg = mtile * 128 + wm * 64 + mt * 16 + kgrp * 4 + r;
                int win = gg >> 6, t = gg & 63;
                int b = win >> 6, whr = (win >> 3) & 7, wwc = win & 7;
                int orow = (b * 64 + whr * 8 + (t >> 3)) * 64 + wwc * 8 + (t & 7);
                out[(size_t)orow * 384 + c] = acc[mt][nt][r] + bias;
            }
        }
    }
}

// ================= Path 2 fallback (fragment-major W, old softmax) ===============
__global__ __launch_bounds__(512, 2)
void win_attn_fused(const float* __restrict__ x, const short* __restrict__ wq_fm,
                    const short* __restrict__ wp_t, const float* __restrict__ b_proj,
                    float* __restrict__ out) {
    __shared__ short Wl[96 * 384];       // both halves concatenated (fragment-major)
    __shared__ short q_s[2][64 * 40];
    __shared__ short k_s[2][64 * 40];
    __shared__ short v_t[2][32 * 72];
    __shared__ short ps[2][64 * 72];

    const int tid   = threadIdx.x;
    const int lane  = tid & 63;
    const int wv    = tid >> 6;
    const int col16 = lane & 15;
    const int kgrp  = lane >> 4;
    const int wwin  = wv >> 2;
    const int q4    = wv & 3;
    const int wm    = q4 >> 1, wn = q4 & 1;

    const int win = blockIdx.x * 2 + wwin;
    const int b = win >> 6, wi = win & 63, whr = wi >> 3, wwc = wi & 7;
    const float* xbase = x + (((b * 64) + whr * 8) * 64 + wwc * 8) * 384;

    const char* Wb = (const char*)Wl + kgrp * 9216 + col16 * 16;

    for (int i = 0; i < 9; ++i) {
        int chunk = wv * 9 + i;
        gload_lds16(wq_fm + chunk * 512 + lane * 8, &Wl[chunk * 512]);
    }
    bf16x8 xf[12];
    {
        int t = q4 * 16 + col16;
        const float* xr = xbase + ((t >> 3) * 64 + (t & 7)) * 384;
#pragma unroll
        for (int kk = 0; kk < 12; ++kk) {
            const float* p0 = xr + kk * 32 + kgrp * 8;
            float4 a = *reinterpret_cast<const float4*>(p0);
            float4 c = *reinterpret_cast<const float4*>(p0 + 4);
            bf16x8 f;
            f[0] = f2bf(a.x); f[1] = f2bf(a.y); f[2] = f2bf(a.z); f[3] = f2bf(a.w);
            f[4] = f2bf(c.x); f[5] = f2bf(c.y); f[6] = f2bf(c.z); f[7] = f2bf(c.w);
            xf[kk] = f;
        }
    }
    f32x4 pacc[2][12];
#pragma unroll
    for (int i = 0; i < 2; ++i)
#pragma unroll
        for (int j = 0; j < 12; ++j) pacc[i][j] = (f32x4){0.f, 0.f, 0.f, 0.f};

    for (int h = 0; h < 12; ++h) {
        drain_vmem();
        __syncthreads();
        f32x4 acc[6];
#pragma unroll
        for (int i = 0; i < 6; ++i) acc[i] = (f32x4){0.f, 0.f, 0.f, 0.f};
#pragma unroll
        for (int kk = 0; kk < 12; ++kk) {
#pragma unroll
            for (int rd = 0; rd < 6; ++rd) {     // rd*16 row base: half rd/3, mt rd%3
                const bf16x8 wf = *reinterpret_cast<const bf16x8*>(
                    Wb + (rd / 3) * 36864 + kk * 768 + (rd % 3) * 256);
                if (rd < 4) acc[rd] = mfma16(wf, xf[kk], acc[rd]);
                else        acc[rd] = mfma16(xf[kk], wf, acc[rd]);
            }
        }
#pragma unroll
        for (int rd = 0; rd < 4; ++rd) {
            short* dst = (rd < 2) ? q_s[wwin] : k_s[wwin];
            *reinterpret_cast<short4_t*>(
                &dst[(q4 * 16 + col16) * 40 + (rd & 1) * 16 + kgrp * 4]) = pack4(acc[rd]);
        }
#pragma unroll
        for (int d = 0; d < 2; ++d)
            *reinterpret_cast<short4_t*>(
                &v_t[wwin][(d * 16 + col16) * 72 + q4 * 16 + kgrp * 4]) = pack4(acc[4 + d]);

        __syncthreads();
        if (h < 11) {
            const short* src = wq_fm + (h + 1) * 36864;
            for (int i = 0; i < 9; ++i) {
                int chunk = wv * 9 + i;
                gload_lds16(src + chunk * 512 + lane * 8, &Wl[chunk * 512]);
            }
        }
        bf16x8 qa = *reinterpret_cast<const bf16x8*>(
            &q_s[wwin][(q4 * 16 + col16) * 40 + kgrp * 8]);
        f32x4 sc[4];
#pragma unroll
        for (int nt = 0; nt < 4; ++nt) {
            bf16x8 kf = *reinterpret_cast<const bf16x8*>(
                &k_s[wwin][(nt * 16 + col16) * 40 + kgrp * 8]);
            f32x4 z = (f32x4){0.f, 0.f, 0.f, 0.f};
            sc[nt] = mfma16(qa, kf, z);
        }
        float mx[4], sm[4], p[4][4];
#pragma unroll
        for (int r = 0; r < 4; ++r)
            mx[r] = fmaxf(fmaxf(sc[0][r], sc[1][r]), fmaxf(sc[2][r], sc[3][r]));
#pragma unroll
        for (int d = 1; d < 16; d <<= 1)
#pragma unroll
            for (int r = 0; r < 4; ++r) mx[r] = fmaxf(mx[r], __shfl_xor(mx[r], d, 16));
#pragma unroll
        for (int r = 0; r < 4; ++r) {
            sm[r] = 0.f;
#pragma unroll
            for (int nt = 0; nt < 4; ++nt) { p[nt][r] = __expf(sc[nt][r] - mx[r]); sm[r] += p[nt][r]; }
        }
#pragma unroll
        for (int d = 1; d < 16; d <<= 1)
#pragma unroll
            for (int r = 0; r < 4; ++r) sm[r] += __shfl_xor(sm[r], d, 16);
#pragma unroll
        for (int r = 0; r < 4; ++r) {
            float inv = 1.0f / sm[r];
            int prow = q4 * 16 + kgrp * 4 + r;
#pragma unroll
            for (int nt = 0; nt < 4; ++nt)
                ps[wwin][prow * 72 + nt * 16 + col16] = f2bf(p[nt][r] * inv);
        }
        f32x4 o2[2];
        o2[0] = (f32x4){0.f, 0.f, 0.f, 0.f};
        o2[1] = (f32x4){0.f, 0.f, 0.f, 0.f};
#pragma unroll
        for (int kt = 0; kt < 2; ++kt) {
            bf16x8 pb = *reinterpret_cast<const bf16x8*>(
                &ps[wwin][(q4 * 16 + col16) * 72 + kt * 32 + kgrp * 8]);
#pragma unroll
            for (int d = 0; d < 2; ++d) {
                bf16x8 va = *reinterpret_cast<const bf16x8*>(
                    &v_t[wwin][(d * 16 + col16) * 72 + kt * 32 + kgrp * 8]);
                o2[d] = mfma16(va, pb, o2[d]);
            }
        }
#pragma unroll
        for (int d = 0; d < 2; ++d)
            *reinterpret_cast<short4_t*>(
                &ps[wwin][(q4 * 16 + col16) * 72 + d * 16 + kgrp * 4]) = pack4(o2[d]);
        __syncthreads();
#pragma unroll
        for (int mt = 0; mt < 2; ++mt) {
            bf16x8 ya = *reinterpret_cast<const bf16x8*>(
                &ps[wwin][(wm * 32 + mt * 16 + col16) * 72 + kgrp * 8]);
#pragma unroll
            for (int nt = 0; nt < 12; ++nt) {
                bf16x8 wb = *reinterpret_cast<const bf16x8*>(
                    &wp_t[(wn * 192 + nt * 16 + col16) * 384 + h * 32 + kgrp * 8]);
                pacc[mt][nt] = mfma16(ya, wb, pacc[mt][nt]);
            }
        }
    }
#pragma unroll
    for (int nt = 0; nt < 12; ++nt) {
        int c = wn * 192 + nt * 16 + col16;
        float bias = b_proj[c];
#pragma unroll
        for (int mt = 0; mt < 2; ++mt) {
#pragma unroll
            for (int r = 0; r < 4; ++r) {
                int token = wm * 32 + mt * 16 + kgrp * 4 + r;
                int hh = whr * 8 + (token >> 3);
                int ww2 = wwc * 8 + (token & 7);
                out[(((b * 64) + hh) * 64 + ww2) * 384 + c] = pacc[mt][nt][r] + bias;
            }
        }
    }
}

extern "C" void kernel_launch(void* const* d_in, const int* in_sizes, int n_in,
                              void* d_out, int out_size, void* d_ws, size_t ws_size,
                              hipStream_t stream) {
    const float* x     = (const float*)d_in[0];
    const float* wqkv  = (const float*)d_in[1];
    const float* wproj = (const float*)d_in[2];
    const float* bproj = (const float*)d_in[3];

    short* wq_fm = (short*)d_ws;                  // 884,736 B (fragment-major)
    short* wp_t  = wq_fm + 12 * 96 * 384;         // 294,912 B
    short* y_sw  = wp_t + 384 * 384;              // 100,663,296 B (path 1 only)
    const size_t need = (size_t)(12 * 96 * 384 + 384 * 384) * 2 + (size_t)1024 * 6 * 128 * 128;

    prep_weights<<<2304, 256, 0, stream>>>(wqkv, wproj, wq_fm, wp_t);
    if (ws_size >= need) {
        qkv_attn<<<1024, 512, 0, stream>>>(x, wq_fm, y_sw);
        proj_gemm<<<dim3(1024, 3), 256, 0, stream>>>(y_sw, wp_t, bproj, (float*)d_out);
    } else {
        win_attn_fused<<<1024, 512, 0, stream>>>(x, wq_fm, wp_t, bproj, (float*)d_out);
    }
}

// Round 10
// 316.932 us; speedup vs baseline: 1.9057x; 1.0043x over previous
//
#include <hip/hip_runtime.h>

// B=32, H=W=64, C=384, ws=8, heads=12, hd=32; windows=2048, N=64 tokens.
// Path 1 (needs ~102MB d_ws):
//   prep -> qkv_attn (2 win/block, 8 waves, half-staged fragment-major Wl,
//                     2 blocks/CU, swapped-scores in-lane softmax)
//        -> proj_gemm (128x128 tiles, window_reverse epilogue)
// Path 2 (fallback, small ws): prep -> win_attn_fused
//
// W LDS layout (fragment-major, per 48-row half): 16B frag of rows' k-slice at
//   byte ((g*12 + kk)*48 + row)*16,  g=kgrp 0..3, kk=0..11 (K-block of 32), row 0..47.
// -> per-lane base computed once; reads use immediate offsets; provably conflict-free.

typedef __attribute__((ext_vector_type(8))) short bf16x8;   // 8 bf16 (4 VGPR) MFMA A/B frag
typedef __attribute__((ext_vector_type(4))) float f32x4;    // MFMA C/D frag
typedef __attribute__((ext_vector_type(4))) short short4_t;

__device__ __forceinline__ short f2bf(float f) {
    union { float f; unsigned u; } v; v.f = f;
    unsigned r = v.u + 0x7fffu + ((v.u >> 16) & 1u);   // RNE
    return (short)(r >> 16);
}

__device__ __forceinline__ unsigned pk2(float a, float b) {   // 2xbf16 dword (a=low)
    return ((unsigned)(unsigned short)f2bf(b) << 16) | (unsigned short)f2bf(a);
}

__device__ __forceinline__ f32x4 mfma16(bf16x8 a, bf16x8 b, f32x4 c) {
    return __builtin_amdgcn_mfma_f32_16x16x32_bf16(a, b, c, 0, 0, 0);
}

__device__ __forceinline__ short4_t pack4(f32x4 v) {
    short4_t s;
    s.x = f2bf(v[0]); s.y = f2bf(v[1]); s.z = f2bf(v[2]); s.w = f2bf(v[3]);
    return s;
}

__device__ __forceinline__ void gload_lds16(const void* g, void* l) {
    __builtin_amdgcn_global_load_lds(
        (const __attribute__((address_space(1))) unsigned int*)g,
        (__attribute__((address_space(3))) unsigned int*)l, 16, 0, 0);
}

// Explicit DMA drain: __syncthreads alone proved insufficient to order
// global_load_lds -> ds_read when the issue->use window is short (r7 race).
__device__ __forceinline__ void drain_vmem() {
    asm volatile("s_waitcnt vmcnt(0)" ::: "memory");
    __builtin_amdgcn_sched_barrier(0);
}

// ---- prep: fragment-major per-head QKV weights (Q rows pre-scaled) + wp^T ----
// wq_fm element idx = ((((h*2 + half)*4 + g)*12 + kk)*48 + row)*8 + e
//   grow = half*48+row: 0..31 = Q dims (x scale), 32..63 = K, 64..95 = V.
//   value = wqkv[k][col], k = kk*32 + g*8 + e, col = (grow>>5)*384 + h*32 + (grow&31).
__global__ void prep_weights(const float* __restrict__ wqkv, const float* __restrict__ wproj,
                             short* __restrict__ wq_fm, short* __restrict__ wp_t) {
    const int QKV_ELEMS = 12 * 96 * 384;
    int i = blockIdx.x * 256 + threadIdx.x;
    if (i < QKV_ELEMS) {
        int e    = i & 7;
        int f    = i >> 3;
        int row  = f % 48;
        int kk   = (f / 48) % 12;
        int g    = (f / (48 * 12)) % 4;
        int half = (f / (48 * 12 * 4)) & 1;
        int h    = f / (48 * 12 * 4 * 2);
        int grow = half * 48 + row;
        int k    = kk * 32 + g * 8 + e;
        int col  = (grow >> 5) * 384 + h * 32 + (grow & 31);
        float w = wqkv[k * 1152 + col];
        if (grow < 32) w *= 0.17677669529663687f;   // 32^-0.5 folded into Q
        wq_fm[i] = f2bf(w);
    } else if (i < QKV_ELEMS + 384 * 384) {
        int j = i - QKV_ELEMS;
        int n = j / 384, k = j % 384;
        wp_t[j] = f2bf(wproj[k * 384 + n]);
    }
}

// ================= Path 1, kernel A: QKV + attention, y -> ws (swizzled) ==========
__global__ __launch_bounds__(512, 4)
void qkv_attn(const float* __restrict__ x, const short* __restrict__ wq_fm,
              short* __restrict__ y_sw) {
    __shared__ short Wl[48 * 384];       // 36,864 B current 48-row half (fragment-major)
    __shared__ short k_s[2][64 * 40];    // K [tok][dim]                10,240 B
    __shared__ short v_t[2][32 * 72];    // V^T [dim][tok]               9,216 B
    __shared__ short ps[2][64 * 72];     // P [q][k] (wave-local rows)  18,432 B
    // total 74,752 B -> 2 blocks/CU, 16 waves/CU

    const int tid   = threadIdx.x;
    const int lane  = tid & 63;
    const int wid   = tid >> 6;      // 0..7
    const int col16 = lane & 15;
    const int kgrp  = lane >> 4;     // 0..3
    const int w     = wid >> 2;      // window within block 0..1
    const int quad  = wid & 3;       // quad in window (owns token-tile quad)

    const int win = blockIdx.x * 2 + w;
    const int b = win >> 6, wi = win & 63, whr = wi >> 3, wwc = wi & 7;
    const float* xbase = x + (((b * 64) + whr * 8) * 64 + wwc * 8) * 384;

    // per-lane W base (fragment-major): frag(g,kk,row=mt*16+c) at base + kk*768 + mt*256
    const char* Wb = (const char*)Wl + kgrp * 9216 + col16 * 16;

    // ---- issue DMA of head-0 half-1 ----
    for (int i = wid; i < 36; i += 8)
        gload_lds16(wq_fm + i * 512 + lane * 8, &Wl[i * 512]);

    // ---- x token-tile -> registers (48 VGPR) ----
    bf16x8 xf[12];
    {
        int t = quad * 16 + col16;
        const float* xr = xbase + ((t >> 3) * 64 + (t & 7)) * 384;
#pragma unroll
        for (int kk = 0; kk < 12; ++kk) {
            const float* p0 = xr + kk * 32 + kgrp * 8;
            float4 a = *reinterpret_cast<const float4*>(p0);
            float4 c = *reinterpret_cast<const float4*>(p0 + 4);
            bf16x8 f;
            f[0] = f2bf(a.x); f[1] = f2bf(a.y); f[2] = f2bf(a.z); f[3] = f2bf(a.w);
            f[4] = f2bf(c.x); f[5] = f2bf(c.y); f[6] = f2bf(c.z); f[7] = f2bf(c.w);
            xf[kk] = f;
        }
    }

    // y addressing: token g, its A-tile row/mtile (proj GEMM image)
    const int g = win * 64 + quad * 16 + col16;
    const int mtile = g >> 7, yrow = g & 127;
    char* ybase = (char*)y_sw + (size_t)mtile * 98304 + (size_t)yrow * 128;

    for (int h = 0; h < 12; ++h) {
        drain_vmem();      // half1(h) DMA (or prefetch) MUST have landed
        __syncthreads();   // BAR1: half1 visible; k_s/v_t/ps free (prev head done)

        // ---- half1: local rows 0-15 = Q d0, 16-31 = Q d1, 32-47 = K d0 ----
        f32x4 aQ0 = (f32x4){0.f, 0.f, 0.f, 0.f};
        f32x4 aQ1 = (f32x4){0.f, 0.f, 0.f, 0.f};
        f32x4 aK0 = (f32x4){0.f, 0.f, 0.f, 0.f};
#pragma unroll
        for (int kk = 0; kk < 12; ++kk) {
            bf16x8 wf0 = *reinterpret_cast<const bf16x8*>(Wb + kk * 768);
            bf16x8 wf1 = *reinterpret_cast<const bf16x8*>(Wb + kk * 768 + 256);
            bf16x8 wf2 = *reinterpret_cast<const bf16x8*>(Wb + kk * 768 + 512);
            aQ0 = mfma16(wf0, xf[kk], aQ0);
            aQ1 = mfma16(wf1, xf[kk], aQ1);
            aK0 = mfma16(wf2, xf[kk], aK0);
        }

        __syncthreads();   // BAR2: all waves done reading half1 -> Wl free

        // ---- issue DMA of half2 ----
        {
            const short* src = wq_fm + h * 36864 + 18432;
            for (int i = wid; i < 36; i += 8)
                gload_lds16(src + i * 512 + lane * 8, &Wl[i * 512]);
        }

        // ---- fill the DMA gap: Q relayout (registers) + K-low scatter ----
        // Q relayout D[dim][tok] -> frag[tok][dim] (A-layout == B-layout transposed)
        bf16x8 qa;
        {
            unsigned A0 = pk2(aQ0[0], aQ0[1]);
            unsigned A1 = pk2(aQ0[2], aQ0[3]);
            unsigned B0 = pk2(aQ1[0], aQ1[1]);
            unsigned B1 = pk2(aQ1[2], aQ1[3]);
            int s0 = ((kgrp & 1) * 2) * 16 + col16;
            int a0 = __shfl((int)A0, s0, 64),      a1 = __shfl((int)A1, s0, 64);
            int a2 = __shfl((int)A0, s0 + 16, 64), a3 = __shfl((int)A1, s0 + 16, 64);
            int b0 = __shfl((int)B0, s0, 64),      b1 = __shfl((int)B1, s0, 64);
            int b2 = __shfl((int)B0, s0 + 16, 64), b3 = __shfl((int)B1, s0 + 16, 64);
            union { int i[4]; bf16x8 v; } qu;
            const bool loHalf = (kgrp < 2);
            qu.i[0] = loHalf ? a0 : b0;
            qu.i[1] = loHalf ? a1 : b1;
            qu.i[2] = loHalf ? a2 : b2;
            qu.i[3] = loHalf ? a3 : b3;
            qa = qu.v;
        }
        // K dims 0..15 scatter (b64), stride 40
        *reinterpret_cast<short4_t*>(
            &k_s[w][(quad * 16 + col16) * 40 + kgrp * 4]) = pack4(aK0);

        drain_vmem();      // half2 DMA MUST have landed (short window -> r7 race)
        __syncthreads();   // BAR3: half2 visible (k_s write also ordered)

        // ---- half2: local rows 0-15 = K d1, 16-31 = V d0, 32-47 = V d1 ----
        f32x4 aK1 = (f32x4){0.f, 0.f, 0.f, 0.f};
        f32x4 aV0 = (f32x4){0.f, 0.f, 0.f, 0.f};
        f32x4 aV1 = (f32x4){0.f, 0.f, 0.f, 0.f};
#pragma unroll
        for (int kk = 0; kk < 12; ++kk) {
            bf16x8 wfK  = *reinterpret_cast<const bf16x8*>(Wb + kk * 768);
            bf16x8 wfV0 = *reinterpret_cast<const bf16x8*>(Wb + kk * 768 + 256);
            bf16x8 wfV1 = *reinterpret_cast<const bf16x8*>(Wb + kk * 768 + 512);
            aK1 = mfma16(wfK, xf[kk], aK1);          // D[dim][tok]
            aV0 = mfma16(xf[kk], wfV0, aV0);         // D[tok][dim]
            aV1 = mfma16(xf[kk], wfV1, aV1);
        }
        // K dims 16..31 scatter
        *reinterpret_cast<short4_t*>(
            &k_s[w][(quad * 16 + col16) * 40 + 16 + kgrp * 4]) = pack4(aK1);
        // V scatter: D[tok][dim] -> v_t[dim][tok]
        *reinterpret_cast<short4_t*>(
            &v_t[w][(col16) * 72 + quad * 16 + kgrp * 4]) = pack4(aV0);
        *reinterpret_cast<short4_t*>(
            &v_t[w][(16 + col16) * 72 + quad * 16 + kgrp * 4]) = pack4(aV1);

        __syncthreads();   // BAR4: K/V complete; half2 consumed -> Wl free for next DMA

        // ---- prefetch next head's half1 (hides under scores/softmax/PV) ----
        if (h < 11) {
            const short* src = wq_fm + (h + 1) * 36864;
            for (int i = wid; i < 36; i += 8)
                gload_lds16(src + i * 512 + lane * 8, &Wl[i * 512]);
        }

        // ---- scores SWAPPED: D[k-tok][q-tok] = mfma(K_frag, Q_frag) ----
        // lane (c,g): sc[nt][r] = S[q = quad*16+c][k = nt*16 + g*4 + r]
        f32x4 sc[4];
#pragma unroll
        for (int nt = 0; nt < 4; ++nt) {
            bf16x8 kf = *reinterpret_cast<const bf16x8*>(
                &k_s[w][(nt * 16 + col16) * 40 + kgrp * 8]);
            f32x4 z = (f32x4){0.f, 0.f, 0.f, 0.f};
            sc[nt] = mfma16(kf, qa, z);
        }
        // ---- softmax: q-row is lane-local (16 vals) + 2 cross-lane steps ----
        float m = sc[0][0];
#pragma unroll
        for (int nt = 0; nt < 4; ++nt)
#pragma unroll
            for (int r = 0; r < 4; ++r) m = fmaxf(m, sc[nt][r]);
        m = fmaxf(m, __shfl_xor(m, 16, 64));
        m = fmaxf(m, __shfl_xor(m, 32, 64));
        float s = 0.f;
#pragma unroll
        for (int nt = 0; nt < 4; ++nt)
#pragma unroll
            for (int r = 0; r < 4; ++r) {
                sc[nt][r] = __expf(sc[nt][r] - m);
                s += sc[nt][r];
            }
        s += __shfl_xor(s, 16, 64);
        s += __shfl_xor(s, 32, 64);
        float inv = 1.0f / s;
        // P store: lane writes its 4x short4 runs P[q=quad*16+c][nt*16 + g*4 .. +3]
#pragma unroll
        for (int nt = 0; nt < 4; ++nt) {
            f32x4 pv;
            pv[0] = sc[nt][0] * inv; pv[1] = sc[nt][1] * inv;
            pv[2] = sc[nt][2] * inv; pv[3] = sc[nt][3] * inv;
            *reinterpret_cast<short4_t*>(
                &ps[w][(quad * 16 + col16) * 72 + nt * 16 + kgrp * 4]) = pack4(pv);
        }
        // ---- PV via mfma(V^T, P) -> D[dim][q]; wave-local ps rows, no barrier ----
        f32x4 o2[2];
        o2[0] = (f32x4){0.f, 0.f, 0.f, 0.f};
        o2[1] = (f32x4){0.f, 0.f, 0.f, 0.f};
#pragma unroll
        for (int kt = 0; kt < 2; ++kt) {
            bf16x8 pb = *reinterpret_cast<const bf16x8*>(
                &ps[w][(quad * 16 + col16) * 72 + kt * 32 + kgrp * 8]);
#pragma unroll
            for (int d = 0; d < 2; ++d) {
                bf16x8 va = *reinterpret_cast<const bf16x8*>(
                    &v_t[w][(d * 16 + col16) * 72 + kt * 32 + kgrp * 8]);
                o2[d] = mfma16(va, pb, o2[d]);
            }
        }
        // ---- y write (swizzled proj-A image): token=col16-row, dims kgrp*4..+3 ----
#pragma unroll
        for (int d = 0; d < 2; ++d) {
            int c0 = h * 32 + d * 16 + kgrp * 4;
            int kchunk = c0 >> 6;
            int koff = (2 * (c0 & 63)) ^ ((yrow & 7) << 4);
            *reinterpret_cast<short4_t*>(ybase + kchunk * 16384 + koff) = pack4(o2[d]);
        }
    }
}

// ================= Path 1, kernel B: out = y @ wp + bias, window_reverse ==========
__global__ __launch_bounds__(256)
void proj_gemm(const short* __restrict__ y_sw, const short* __restrict__ wp_t,
               const float* __restrict__ b_proj, float* __restrict__ out) {
    __shared__ short At[2][128 * 64];   // 2 x 16 KiB swizzled A tiles

    const int tid = threadIdx.x, lane = tid & 63, wv = tid >> 6;
    const int col16 = lane & 15, kgrp = lane >> 4;
    const int wm = wv >> 1, wn = wv & 1;
    const int mtile = blockIdx.x;       // 0..1023
    const int nblk  = blockIdx.y;       // 0..2

    const short* asrc = y_sw + (size_t)mtile * 6 * 128 * 64;

    // prologue: stage kchunk 0
    for (int i = wv; i < 16; i += 4)
        gload_lds16(asrc + i * 512 + lane * 8, &At[0][i * 512]);

    const short* bptr[4];
#pragma unroll
    for (int nt = 0; nt < 4; ++nt)
        bptr[nt] = wp_t + (size_t)(nblk * 128 + wn * 64 + nt * 16 + col16) * 384;

    f32x4 acc[4][4];
#pragma unroll
    for (int i = 0; i < 4; ++i)
#pragma unroll
        for (int j = 0; j < 4; ++j) acc[i][j] = (f32x4){0.f, 0.f, 0.f, 0.f};

    int cur = 0;
    for (int ks = 0; ks < 6; ++ks) {
        drain_vmem();                  // buf[cur]'s DMA must have landed
        __syncthreads();
        if (ks < 5) {
            const short* src = asrc + (ks + 1) * (128 * 64);
            for (int i = wv; i < 16; i += 4)
                gload_lds16(src + i * 512 + lane * 8, &At[cur ^ 1][i * 512]);
        }
#pragma unroll
        for (int kk = 0; kk < 2; ++kk) {
            const int kbyte = kk * 64 + kgrp * 16;
            bf16x8 af[4];
#pragma unroll
            for (int mt = 0; mt < 4; ++mt) {
                const int r = wm * 64 + mt * 16 + col16;
                af[mt] = *reinterpret_cast<const bf16x8*>(
                    (const char*)At[cur] + r * 128 + (kbyte ^ ((r & 7) << 4)));
            }
#pragma unroll
            for (int nt = 0; nt < 4; ++nt) {
                bf16x8 bf = *reinterpret_cast<const bf16x8*>(bptr[nt] + ks * 64 + kk * 32 + kgrp * 8);
#pragma unroll
                for (int mt = 0; mt < 4; ++mt)
                    acc[mt][nt] = mfma16(af[mt], bf, acc[mt][nt]);
            }
        }
        cur ^= 1;
    }

    // epilogue: bias + window_reverse scatter
#pragma unroll
    for (int nt = 0; nt < 4; ++nt) {
        int c = nblk * 128 + wn * 64 + nt * 16 + col16;
        float bias = b_proj[c];
#pragma unroll
        for (int mt = 0; mt < 4; ++mt) {
#pragma unroll
            for (int r = 0; r < 4; ++r) {
                int gg = mtile * 128 + wm * 64 + mt * 16 + kgrp * 4 + r;
                int win = gg >> 6, t = gg & 63;
                int b = win >> 6, whr = (win >> 3) & 7, wwc = win & 7;
                int orow = (b * 64 + whr * 8 + (t >> 3)) * 64 + wwc * 8 + (t & 7);
                out[(size_t)orow * 384 + c] = acc[mt][nt][r] + bias;
            }
        }
    }
}

// ================= Path 2 fallback (fragment-major W, old softmax) ===============
__global__ __launch_bounds__(512, 2)
void win_attn_fused(const float* __restrict__ x, const short* __restrict__ wq_fm,
                    const short* __restrict__ wp_t, const float* __restrict__ b_proj,
                    float* __restrict__ out) {
    __shared__ short Wl[96 * 384];       // both halves concatenated (fragment-major)
    __shared__ short q_s[2][64 * 40];
    __shared__ short k_s[2][64 * 40];
    __shared__ short v_t[2][32 * 72];
    __shared__ short ps[2][64 * 72];

    const int tid   = threadIdx.x;
    const int lane  = tid & 63;
    const int wv    = tid >> 6;
    const int col16 = lane & 15;
    const int kgrp  = lane >> 4;
    const int wwin  = wv >> 2;
    const int q4    = wv & 3;
    const int wm    = q4 >> 1, wn = q4 & 1;

    const int win = blockIdx.x * 2 + wwin;
    const int b = win >> 6, wi = win & 63, whr = wi >> 3, wwc = wi & 7;
    const float* xbase = x + (((b * 64) + whr * 8) * 64 + wwc * 8) * 384;

    const char* Wb = (const char*)Wl + kgrp * 9216 + col16 * 16;

    for (int i = 0; i < 9; ++i) {
        int chunk = wv * 9 + i;
        gload_lds16(wq_fm + chunk * 512 + lane * 8, &Wl[chunk * 512]);
    }
    bf16x8 xf[12];
    {
        int t = q4 * 16 + col16;
        const float* xr = xbase + ((t >> 3) * 64 + (t & 7)) * 384;
#pragma unroll
        for (int kk = 0; kk < 12; ++kk) {
            const float* p0 = xr + kk * 32 + kgrp * 8;
            float4 a = *reinterpret_cast<const float4*>(p0);
            float4 c = *reinterpret_cast<const float4*>(p0 + 4);
            bf16x8 f;
            f[0] = f2bf(a.x); f[1] = f2bf(a.y); f[2] = f2bf(a.z); f[3] = f2bf(a.w);
            f[4] = f2bf(c.x); f[5] = f2bf(c.y); f[6] = f2bf(c.z); f[7] = f2bf(c.w);
            xf[kk] = f;
        }
    }
    f32x4 pacc[2][12];
#pragma unroll
    for (int i = 0; i < 2; ++i)
#pragma unroll
        for (int j = 0; j < 12; ++j) pacc[i][j] = (f32x4){0.f, 0.f, 0.f, 0.f};

    for (int h = 0; h < 12; ++h) {
        drain_vmem();
        __syncthreads();
        f32x4 acc[6];
#pragma unroll
        for (int i = 0; i < 6; ++i) acc[i] = (f32x4){0.f, 0.f, 0.f, 0.f};
#pragma unroll
        for (int kk = 0; kk < 12; ++kk) {
#pragma unroll
            for (int rd = 0; rd < 6; ++rd) {     // rd*16 row base: half rd/3, mt rd%3
                const bf16x8 wf = *reinterpret_cast<const bf16x8*>(
                    Wb + (rd / 3) * 36864 + kk * 768 + (rd % 3) * 256);
                if (rd < 4) acc[rd] = mfma16(wf, xf[kk], acc[rd]);
                else        acc[rd] = mfma16(xf[kk], wf, acc[rd]);
            }
        }
#pragma unroll
        for (int rd = 0; rd < 4; ++rd) {
            short* dst = (rd < 2) ? q_s[wwin] : k_s[wwin];
            *reinterpret_cast<short4_t*>(
                &dst[(q4 * 16 + col16) * 40 + (rd & 1) * 16 + kgrp * 4]) = pack4(acc[rd]);
        }
#pragma unroll
        for (int d = 0; d < 2; ++d)
            *reinterpret_cast<short4_t*>(
                &v_t[wwin][(d * 16 + col16) * 72 + q4 * 16 + kgrp * 4]) = pack4(acc[4 + d]);

        __syncthreads();
        if (h < 11) {
            const short* src = wq_fm + (h + 1) * 36864;
            for (int i = 0; i < 9; ++i) {
                int chunk = wv * 9 + i;
                gload_lds16(src + chunk * 512 + lane * 8, &Wl[chunk * 512]);
            }
        }
        bf16x8 qa = *reinterpret_cast<const bf16x8*>(
            &q_s[wwin][(q4 * 16 + col16) * 40 + kgrp * 8]);
        f32x4 sc[4];
#pragma unroll
        for (int nt = 0; nt < 4; ++nt) {
            bf16x8 kf = *reinterpret_cast<const bf16x8*>(
                &k_s[wwin][(nt * 16 + col16) * 40 + kgrp * 8]);
            f32x4 z = (f32x4){0.f, 0.f, 0.f, 0.f};
            sc[nt] = mfma16(qa, kf, z);
        }
        float mx[4], sm[4], p[4][4];
#pragma unroll
        for (int r = 0; r < 4; ++r)
            mx[r] = fmaxf(fmaxf(sc[0][r], sc[1][r]), fmaxf(sc[2][r], sc[3][r]));
#pragma unroll
        for (int d = 1; d < 16; d <<= 1)
#pragma unroll
            for (int r = 0; r < 4; ++r) mx[r] = fmaxf(mx[r], __shfl_xor(mx[r], d, 16));
#pragma unroll
        for (int r = 0; r < 4; ++r) {
            sm[r] = 0.f;
#pragma unroll
            for (int nt = 0; nt < 4; ++nt) { p[nt][r] = __expf(sc[nt][r] - mx[r]); sm[r] += p[nt][r]; }
        }
#pragma unroll
        for (int d = 1; d < 16; d <<= 1)
#pragma unroll
            for (int r = 0; r < 4; ++r) sm[r] += __shfl_xor(sm[r], d, 16);
#pragma unroll
        for (int r = 0; r < 4; ++r) {
            float inv = 1.0f / sm[r];
            int prow = q4 * 16 + kgrp * 4 + r;
#pragma unroll
            for (int nt = 0; nt < 4; ++nt)
                ps[wwin][prow * 72 + nt * 16 + col16] = f2bf(p[nt][r] * inv);
        }
        f32x4 o2[2];
        o2[0] = (f32x4){0.f, 0.f, 0.f, 0.f};
        o2[1] = (f32x4){0.f, 0.f, 0.f, 0.f};
#pragma unroll
        for (int kt = 0; kt < 2; ++kt) {
            bf16x8 pb = *reinterpret_cast<const bf16x8*>(
                &ps[wwin][(q4 * 16 + col16) * 72 + kt * 32 + kgrp * 8]);
#pragma unroll
            for (int d = 0; d < 2; ++d) {
                bf16x8 va = *reinterpret_cast<const bf16x8*>(
                    &v_t[wwin][(d * 16 + col16) * 72 + kt * 32 + kgrp * 8]);
                o2[d] = mfma16(va, pb, o2[d]);
            }
        }
#pragma unroll
        for (int d = 0; d < 2; ++d)
            *reinterpret_cast<short4_t*>(
                &ps[wwin][(q4 * 16 + col16) * 72 + d * 16 + kgrp * 4]) = pack4(o2[d]);
        __syncthreads();
#pragma unroll
        for (int mt = 0; mt < 2; ++mt) {
            bf16x8 ya = *reinterpret_cast<const bf16x8*>(
                &ps[wwin][(wm * 32 + mt * 16 + col16) * 72 + kgrp * 8]);
#pragma unroll
            for (int nt = 0; nt < 12; ++nt) {
                bf16x8 wb = *reinterpret_cast<const bf16x8*>(
                    &wp_t[(wn * 192 + nt * 16 + col16) * 384 + h * 32 + kgrp * 8]);
                pacc[mt][nt] = mfma16(ya, wb, pacc[mt][nt]);
            }
        }
    }
#pragma unroll
    for (int nt = 0; nt < 12; ++nt) {
        int c = wn * 192 + nt * 16 + col16;
        float bias = b_proj[c];
#pragma unroll
        for (int mt = 0; mt < 2; ++mt) {
#pragma unroll
            for (int r = 0; r < 4; ++r) {
                int token = wm * 32 + mt * 16 + kgrp * 4 + r;
                int hh = whr * 8 + (token >> 3);
                int ww2 = wwc * 8 + (token & 7);
                out[(((b * 64) + hh) * 64 + ww2) * 384 + c] = pacc[mt][nt][r] + bias;
            }
        }
    }
}

extern "C" void kernel_launch(void* const* d_in, const int* in_sizes, int n_in,
                              void* d_out, int out_size, void* d_ws, size_t ws_size,
                              hipStream_t stream) {
    const float* x     = (const float*)d_in[0];
    const float* wqkv  = (const float*)d_in[1];
    const float* wproj = (const float*)d_in[2];
    const float* bproj = (const float*)d_in[3];

    short* wq_fm = (short*)d_ws;                  // 884,736 B (fragment-major)
    short* wp_t  = wq_fm + 12 * 96 * 384;         // 294,912 B
    short* y_sw  = wp_t + 384 * 384;              // 100,663,296 B (path 1 only)
    const size_t need = (size_t)(12 * 96 * 384 + 384 * 384) * 2 + (size_t)1024 * 6 * 128 * 128;

    prep_weights<<<2304, 256, 0, stream>>>(wqkv, wproj, wq_fm, wp_t);
    if (ws_size >= need) {
        qkv_attn<<<1024, 512, 0, stream>>>(x, wq_fm, y_sw);
        proj_gemm<<<dim3(1024, 3), 256, 0, stream>>>(y_sw, wp_t, bproj, (float*)d_out);
    } else {
        win_attn_fused<<<1024, 512, 0, stream>>>(x, wq_fm, wp_t, bproj, (float*)d_out);
    }
}